// Round 6
// baseline (468.777 us; speedup 1.0000x reference)
//
#include <hip/hip_runtime.h>
#include <hip/hip_bf16.h>

typedef _Float16 f16;
typedef _Float16 f16x4 __attribute__((ext_vector_type(4)));
typedef _Float16 f16x8 __attribute__((ext_vector_type(8)));
typedef float    f32x4 __attribute__((ext_vector_type(4)));

static __device__ __forceinline__ float bf2f(__hip_bfloat16 x) { return __bfloat162float(x); }
// dual-dtype float load/store: f32flag=1 -> float*, else bf16*
static __device__ __forceinline__ float ldf(const void* p, long i, int f32flag) {
    return f32flag ? ((const float*)p)[i] : bf2f(((const __hip_bfloat16*)p)[i]);
}
static __device__ __forceinline__ void stf(void* p, long i, int f32flag, float v) {
    if (f32flag) ((float*)p)[i] = v;
    else ((__hip_bfloat16*)p)[i] = __float2bfloat16(v);
}
// async global->LDS, 16B per lane; LDS dest is wave-uniform base + lane*16
static __device__ __forceinline__ void gl2lds16(const f16* g, f16* l) {
    __builtin_amdgcn_global_load_lds(
        (const __attribute__((address_space(1))) unsigned int*)(const void*)g,
        (__attribute__((address_space(3))) unsigned int*)(void*)l, 16, 0, 0);
}

// ---------------- workspace layout (bytes) ----------------
#define OFF_LOGITS 0L                               // S/logits: 32000 x 1024 f16
#define SZ_LOGITS  (32000L * 1024 * 2)
#define OFF_FEAT   (OFF_LOGITS + SZ_LOGITS)         // feat: 32000 x 768 f16
#define SZ_FEAT    (32000L * 768 * 2)
#define OFF_ATTF   (OFF_FEAT + SZ_FEAT)             // att_feat: 32000 x 768 f16
#define SZ_ATTF    (32000L * 768 * 2)
#define OFF_AWT    (OFF_ATTF + SZ_ATTF)             // attn_w^T: 1024 x 768 f16 (rows>=999 zero)
#define SZ_AWT     (1024L * 768 * 2)
#define OFF_WCT    (OFF_AWT + SZ_AWT)               // Wc^T: 128 x 1536 f16 (rows>=75 zero)
#define SZ_WCT     (128L * 1536 * 2)
#define OFF_BIAS   (OFF_WCT + SZ_WCT)               // f32[75] (padded 512)
#define OFF_FLAG   (OFF_BIAS + 512)                 // int flags[2]
#define OFF_FEATT  (OFF_FLAG + 64)                  // feat^T per batch: 32 x 768 x 1024 f16
#define SZ_FEATT   (32L * 768 * 1024 * 2)
#define NEED_A     (OFF_FEATT + SZ_FEATT)           // ~216 MB

// ---------------- detection (cheap sampling) ----------------
// flags[0]: 0=int32, 1=int8/bool, 2=bf16, 3=int64, 4=f32   flags[1]: 1=f32 floats, 0=bf16 floats
__global__ void detect_kernel(const unsigned int* __restrict__ fv,
                              const unsigned int* __restrict__ m,
                              int mwords, int* __restrict__ flags)
{
    __shared__ int cnt, bits;
    int t = threadIdx.x;
    if (t == 0) { cnt = 0; bits = 0; }
    __syncthreads();
    int c = 0;
    for (int k = t; k < 2048; k += 256) {
        unsigned int w = fv[k];
        unsigned int h0 = w & 0xffffu, h1 = w >> 16;
        unsigned int e0 = (h0 >> 7) & 0xffu, e1 = (h1 >> 7) & 0xffu;
        c += (h0 == 0u || (e0 >= 100u && e0 <= 135u)) ? 1 : 0;
        c += (h1 == 0u || (e1 >= 100u && e1 <= 135u)) ? 1 : 0;
    }
    atomicAdd(&cnt, c);
    int lb = 0;
    for (int k = t; k < mwords; k += 256) {
        unsigned int w = m[k];
        if (w > 1u) lb |= 1;                        // some word not in {0,1}
        if ((k & 1) && w != 0u) lb |= 2;            // odd word nonzero
        unsigned int lo = w & 0xffffu, hi = w >> 16;
        if (!((lo == 0u || lo == 0x3f80u) && (hi == 0u || hi == 0x3f80u))) lb |= 4;
        if (lo == 0x3f80u) lb |= 8;
    }
    if (lb) atomicOr(&bits, lb);
    __syncthreads();
    if (t == 0) {
        int b = bits, f;
        if (!(b & 1))      f = (b & 2) ? 0 : 3;     // words all {0,1}: int32 vs int64
        else if (!(b & 4)) f = (b & 8) ? 2 : 4;     // {0,0x3f80} halves: bf16 vs f32
        else               f = 1;                    // raw bytes
        flags[0] = f;
        flags[1] = (cnt < 3900) ? 1 : 0;            // bf16 ~4096 hits, f32 ~2335
    }
}

// ---------------- gather: build feat AND featT via LDS-staged fv slab ----------------
__global__ __launch_bounds__(256) void build_feat_kernel(
    const void* __restrict__ fv, const int* __restrict__ x_idx,
    const void* __restrict__ maskp, const int* __restrict__ flags,
    int xstride, int mstride, f16* __restrict__ feat, f16* __restrict__ featT)
{
    __shared__ f16 sfv[15360];                      // [(c*12+h)*20 + x]
    __shared__ int sx[1500];                        // [n_local*12 + h]
    __shared__ unsigned char sm[1500];
    int b = blockIdx.y, n0 = blockIdx.x * 125;
    int t = threadIdx.x;
    int isf = flags[1], fm = flags[0];
    for (int k = t; k < 15360; k += 256)
        sfv[k] = (f16)ldf(fv, (long)b * 15360 + k, isf);
    for (int k = t; k < 1500; k += 256) {
        int n = k / 12, h = k - n * 12;
        sx[k] = x_idx[(long)(n0 + n) * xstride + h];
        long mb = (long)(n0 + n) * mstride + h;
        int mv;
        if (fm == 0)      mv = ((const int*)maskp)[mb] != 0;
        else if (fm == 1) mv = ((const unsigned char*)maskp)[mb] != 0;
        else if (fm == 2) mv = ((const unsigned short*)maskp)[mb] != 0;
        else if (fm == 3) mv = ((const int*)maskp)[mb * 2] != 0;
        else              mv = ((const unsigned int*)maskp)[mb] != 0;
        sm[k] = (unsigned char)mv;
    }
    __syncthreads();
    // feat rows (row-major): 125 rows x 192 vec4-chunks
    for (int q = t; q < 24000; q += 256) {
        int n = q / 192, r = q - n * 192;
        int e0 = r * 4;
        f16x4 v;
        #pragma unroll
        for (int j = 0; j < 4; j++) {
            int e = e0 + j;
            int h = e % 12;
            int kk = n * 12 + h;
            v[j] = sm[kk] ? (f16)0.f : sfv[e * 20 + sx[kk]];
        }
        *(f16x4*)(feat + ((long)(b * 1000 + n0 + n)) * 768 + e0) = v;
    }
    // featT (d-major): 768 d x 125 n, coalesced along n
    if (featT) {
        f16* ftb = featT + (long)b * 786432;
        for (int q = t; q < 98304; q += 256) {       // 768 x 128 slots
            int d = q >> 7, nl = q & 127;
            if (nl < 125) {
                int h = d % 12;
                int kk = nl * 12 + h;
                f16 v = sm[kk] ? (f16)0.f : sfv[d * 20 + sx[kk]];
                ftb[(long)d * 1024 + n0 + nl] = v;
            }
        }
    }
}

// ---------------- transpose into f16; SRC=1: dual-float input ----------------
template<int SRC>
__global__ __launch_bounds__(256) void transpose_kernel(
    const void* __restrict__ inp, f16* __restrict__ out, const int* __restrict__ flags,
    int R, int C, int inR, int inC, int ldin, int ldout, long sIn, long sOut)
{
    __shared__ f16 tile[32][33];
    int isf = SRC ? flags[1] : 0;
    int c0 = blockIdx.x * 32, r0 = blockIdx.y * 32;
    int tx = threadIdx.x & 31, ty = threadIdx.x >> 5;
    #pragma unroll
    for (int i = ty; i < 32; i += 8) {
        int r = r0 + i, c = c0 + tx;
        float v = 0.f;
        if (r < inR && c < inC) {
            long idx = (long)blockIdx.z * sIn + (long)r * ldin + c;
            v = SRC ? ldf(inp, idx, isf) : (float)((const f16*)inp)[idx];
        }
        tile[i][tx] = (f16)v;
    }
    __syncthreads();
    #pragma unroll
    for (int i = ty; i < 32; i += 8) {
        int oc = c0 + i, orw = r0 + tx;
        if (oc < C && orw < R)
            out[(long)blockIdx.z * sOut + (long)oc * ldout + orw] = tile[tx][i];
    }
}

// ---------------- combined classifier/regressor weights (128 rows, zero-padded) ----------------
__global__ __launch_bounds__(256) void build_wc_kernel(
    const void* __restrict__ cls_w, const void* __restrict__ cls_b,
    const void* __restrict__ reg_w, const void* __restrict__ reg_b,
    const int* __restrict__ flags, f16* __restrict__ wcT, float* __restrict__ biasc)
{
    int isf = flags[1];
    int idx = blockIdx.x * 256 + threadIdx.x;       // 128*1536 = 196608
    if (idx < 128 * 1536) {
        int c = idx / 1536, k = idx - c * 1536;
        float v = 0.f;
        if (c < 2)       v = ldf(cls_w, (long)k * 2 + c, isf);
        else if (c < 75) v = ldf(reg_w, (long)k * 73 + (c - 2), isf);
        wcT[idx] = (f16)v;                           // wcT[c][k], ld 1536
    }
    if (idx < 75)
        biasc[idx] = (idx < 2) ? ldf(cls_b, idx, isf) : ldf(reg_b, idx - 2, isf);
}

// ---------------- softmax over 999 + shifted scatter (in place, register-resident) ----------------
__global__ __launch_bounds__(256) void softmax_kernel(
    f16* __restrict__ buf, const void* __restrict__ attn_b, const int* __restrict__ flags)
{
    int i = blockIdx.x, b = blockIdx.y;
    f16* row = buf + ((long)(b * 1000 + i)) * 1024;
    __shared__ float red[8];
    int isf = flags[1];
    int t = threadIdx.x;
    int k0 = t * 4;
    f16x4 rv = *(const f16x4*)(row + k0);            // all reads before any write
    float v[4];
    float lmax = -3.4e38f;
    #pragma unroll
    for (int j = 0; j < 4; j++) {
        int k = k0 + j;
        float x = (k < 999) ? (float)rv[j] + ldf(attn_b, k, isf) : -3.4e38f;
        v[j] = x;
        lmax = fmaxf(lmax, x);
    }
    #pragma unroll
    for (int o = 32; o > 0; o >>= 1) lmax = fmaxf(lmax, __shfl_down(lmax, o, 64));
    if ((t & 63) == 0) red[t >> 6] = lmax;
    __syncthreads();
    float gmax = fmaxf(fmaxf(red[0], red[1]), fmaxf(red[2], red[3]));
    float lsum = 0.f;
    #pragma unroll
    for (int j = 0; j < 4; j++) {
        int k = k0 + j;
        float e = (k < 999) ? __expf(v[j] - gmax) : 0.f;
        v[j] = e;
        lsum += e;
    }
    #pragma unroll
    for (int o = 32; o > 0; o >>= 1) lsum += __shfl_down(lsum, o, 64);
    if ((t & 63) == 0) red[4 + (t >> 6)] = lsum;
    __syncthreads();
    float inv = 1.f / (red[4] + red[5] + red[6] + red[7]);
    #pragma unroll
    for (int j = 0; j < 4; j++) {
        int k = k0 + j;
        if (k < 999) row[k + (k >= i ? 1 : 0)] = (f16)(v[j] * inv);
    }
    if (t == 0) row[i] = (f16)0.f;                   // zero diagonal
}

// ---------------- MFMA GEMM ----------------
// non-BKM: unguarded global_load_lds(16B) staging into XOR-swizzled unpadded LDS.
// TM in {64,128}, TN in {128,256}.
// SWZ: 0 none; 2 GEMM1 m-group->XCD (grid 2048 flat, TM=64);
//      3 legacy; 4 GEMM2 batch->XCD (grid 1536 flat, TM=64).
enum { OUT_F16 = 0, OUT_FINAL = 1 };

template<int MODE, bool CAT, bool BKM, int TM, int TN, int SWZ>
__global__ __launch_bounds__(256, 2) void gemm_kernel(
    const f16* __restrict__ A, const f16* __restrict__ A2, int lda,
    const f16* __restrict__ Bt, int ldb,
    void* __restrict__ Cout, int ldc,
    int M, int Nc, int K,
    long sA, long sB, long sC,
    const float* __restrict__ bias, const void* __restrict__ anchors,
    const int* __restrict__ flags)
{
    int t = threadIdx.x;
    int bx, by, bz;
    if constexpr (SWZ == 2) {          // grid 2048 flat: 500 m-groups x 4 n-blocks
        int bid = blockIdx.x;
        int xcd = bid & 7, s = bid >> 3;             // s in [0,256)
        int g = xcd + 8 * (s >> 2);                  // XCD owns groups g == xcd (mod 8)
        if (g >= 500) return;                        // 48 idle blocks
        by = g; bx = s & 3; bz = 0;
    } else if constexpr (SWZ == 4) {   // grid 1536 flat: 8 XCD x 4 batches x (16m x 3n)
        int bid = blockIdx.x;
        int xcd = bid & 7, s = bid >> 3;             // s in [0,192)
        bz = xcd * 4 + s / 48;
        int wv = s % 48;
        by = wv / 3; bx = wv - by * 3;
    } else { bx = blockIdx.x; by = blockIdx.y; bz = blockIdx.z; }

    int m0 = by * TM, n0 = bx * TN;
    int z = bz;
    A  += (long)z * sA;
    if (CAT) A2 += (long)z * sA;
    Bt += (long)z * sB;
    int w = t >> 6, lane = t & 63;
    constexpr int NJ = (TM == 128 && TN == 256) ? 8 : ((TN == 256) ? 4 : ((TM == 128) ? 4 : 2));
    int wm = (TM == 128) ? (w & 1) * 64 : 0;
    int wn;
    if constexpr (TM == 128 && TN == 256) wn = (w >> 1) * 128;
    else if constexpr (TN == 256)         wn = w * 64;
    else if constexpr (TM == 128)         wn = (w >> 1) * 64;
    else                                  wn = w * 32;

    int lr = lane & 15, lq = lane >> 4;

    const f32x4 zero4 = {0.f, 0.f, 0.f, 0.f};
    f32x4 acc[4][NJ];
    #pragma unroll
    for (int i = 0; i < 4; i++)
        #pragma unroll
        for (int j = 0; j < NJ; j++) acc[i][j] = zero4;

    if constexpr (!BKM) {
        constexpr int AI = TM / 64;                  // A staging iterations
        constexpr int BI = TN / 64;                  // B staging iterations
        __shared__ __align__(16) f16 As[TM * 32];
        __shared__ __align__(16) f16 Bs[TN * 32];
        long aoff[AI], boff[BI];
        f16 *lA[AI], *lB[BI];
        #pragma unroll
        for (int i = 0; i < AI; i++) {
            int q = t + i * 256;
            int row = q >> 2, slot = q & 3;
            int c = slot ^ ((row >> 1) & 3);
            aoff[i] = (long)(m0 + row) * lda + c * 8;
            lA[i] = &As[(i * 256 + w * 64) * 8];     // wave-uniform base
        }
        #pragma unroll
        for (int i = 0; i < BI; i++) {
            int q = t + i * 256;
            int row = q >> 2, slot = q & 3;
            int c = slot ^ ((row >> 1) & 3);
            boff[i] = (long)(n0 + row) * ldb + c * 8;
            lB[i] = &Bs[(i * 256 + w * 64) * 8];
        }
        for (int k0 = 0; k0 < K; k0 += 32) {
            const f16* Ak = A; int kk = k0;
            if (CAT && k0 >= 768) { Ak = A2; kk = k0 - 768; }
            __syncthreads();
            #pragma unroll
            for (int i = 0; i < AI; i++) gl2lds16(Ak + aoff[i] + kk, lA[i]);
            #pragma unroll
            for (int i = 0; i < BI; i++) gl2lds16(Bt + boff[i] + k0, lB[i]);
            __syncthreads();                         // drains vmcnt before barrier
            f16x8 af[4], bfr[NJ];
            #pragma unroll
            for (int i = 0; i < 4; i++) {
                int r = wm + i * 16 + lr;
                af[i] = *(const f16x8*)&As[r * 32 + (lq ^ ((r >> 1) & 3)) * 8];
            }
            #pragma unroll
            for (int j = 0; j < NJ; j++) {
                int r = wn + j * 16 + lr;
                bfr[j] = *(const f16x8*)&Bs[r * 32 + (lq ^ ((r >> 1) & 3)) * 8];
            }
            #pragma unroll
            for (int i = 0; i < 4; i++)
                #pragma unroll
                for (int j = 0; j < NJ; j++)
                    acc[i][j] = __builtin_amdgcn_mfma_f32_16x16x32_f16(af[i], bfr[j], acc[i][j], 0, 0, 0);
        }
    } else {
        __shared__ __align__(16) f16 As[128 * 40];
        __shared__ __align__(16) f16 Bs[32 * 132];
        const f16x8 zero8 = {(f16)0, (f16)0, (f16)0, (f16)0, (f16)0, (f16)0, (f16)0, (f16)0};
        const f16x4 zero4h = {(f16)0, (f16)0, (f16)0, (f16)0};
        for (int k0 = 0; k0 < K; k0 += 32) {
            __syncthreads();
            #pragma unroll
            for (int i = 0; i < 2; i++) {
                int q = t + i * 256;
                { int row = q >> 2, kc = (q & 3) * 8;
                  f16x8 av = zero8;
                  if ((m0 + row) < M && (k0 + kc) < K)
                      av = *(const f16x8*)(A + (long)(m0 + row) * lda + k0 + kc);
                  *(f16x8*)&As[row * 40 + kc] = av; }
                { int kr = q >> 4, nc = (q & 15) * 8;
                  f16x4 b0 = zero4h, b1 = zero4h;
                  if ((k0 + kr) < K && (n0 + nc) < Nc) {
                      const f16* p = Bt + (long)(k0 + kr) * ldb + n0 + nc;
                      b0 = *(const f16x4*)p;
                      b1 = *(const f16x4*)(p + 4);
                  }
                  *(f16x4*)&Bs[kr * 132 + nc]     = b0;
                  *(f16x4*)&Bs[kr * 132 + nc + 4] = b1; }
            }
            __syncthreads();
            f16x8 af[4], bfr[NJ];
            #pragma unroll
            for (int i = 0; i < 4; i++)
                af[i] = *(const f16x8*)&As[(wm + i * 16 + lr) * 40 + lq * 8];
            #pragma unroll
            for (int j = 0; j < NJ; j++)
                #pragma unroll
                for (int jj = 0; jj < 8; jj++)
                    bfr[j][jj] = Bs[(lq * 8 + jj) * 132 + wn + j * 16 + lr];
            #pragma unroll
            for (int i = 0; i < 4; i++)
                #pragma unroll
                for (int j = 0; j < NJ; j++)
                    acc[i][j] = __builtin_amdgcn_mfma_f32_16x16x32_f16(af[i], bfr[j], acc[i][j], 0, 0, 0);
        }
    }

    int isf = (MODE == OUT_FINAL) ? flags[1] : 0;
    #pragma unroll
    for (int i = 0; i < 4; i++) {
        #pragma unroll
        for (int j = 0; j < NJ; j++) {
            #pragma unroll
            for (int r = 0; r < 4; r++) {
                int gm = m0 + wm + i * 16 + lq * 4 + r;   // C/D: row = quad*4+reg
                int gn = n0 + wn + j * 16 + lr;           //      col = lane&15
                if (MODE == OUT_F16) {
                    if (gm < M && gn < Nc)
                        ((f16*)Cout)[(long)z * sC + (long)gm * ldc + gn] = (f16)acc[i][j][r];
                } else {
                    if (gn < Nc) {                         // Nc=75 real cols
                        float v = acc[i][j][r] + bias[gn];
                        int oc = (gn < 2) ? gn : gn + 2;   // skip anchor cols 2,3
                        if (gn >= 2) v += ldf(anchors, (long)(gm % 1000) * 77 + oc, isf);
                        stf(Cout, (long)gm * 77 + oc, isf, v);
                    } else if (gn < 77) {                  // wasted lanes fill anchor cols 2,3
                        int oc = gn - 73;                  // 75->2, 76->3
                        stf(Cout, (long)gm * 77 + oc, isf,
                            ldf(anchors, (long)(gm % 1000) * 77 + oc, isf));
                    }
                }
            }
        }
    }
}

extern "C" void kernel_launch(void* const* d_in, const int* in_sizes, int n_in,
                              void* d_out, int out_size, void* d_ws, size_t ws_size,
                              hipStream_t stream)
{
    const void* fv      = d_in[0];
    const void* attn_w  = d_in[1];
    const void* attn_b  = d_in[2];
    const void* cls_w   = d_in[3];
    const void* cls_b   = d_in[4];
    const void* reg_w   = d_in[5];
    const void* reg_b   = d_in[6];
    const void* anchors = d_in[7];
    const int*  x_idx   = (const int*)d_in[10];
    const void* maskp   = d_in[11];
    int xstride = (in_sizes[10] < 768000) ? 12 : 768;   // un-broadcast fallback
    int mstride = (in_sizes[11] < 768000) ? 12 : 768;
    int mwords  = in_sizes[11] / 4;                      // int8 worst case, stay in bounds
    if (mwords > 4096) mwords = 4096;

    char* ws = (char*)d_ws;
    f16*   logits = (f16*)(ws + OFF_LOGITS);
    f16*   feat   = (f16*)(ws + OFF_FEAT);
    f16*   attf   = (f16*)(ws + OFF_ATTF);
    f16*   awT    = (f16*)(ws + OFF_AWT);
    f16*   wcT    = (f16*)(ws + OFF_WCT);
    float* biasc  = (float*)(ws + OFF_BIAS);
    int*   flags  = (int*)(ws + OFF_FLAG);
    f16*   featT  = (f16*)(ws + OFF_FEATT);
    bool bigws = ws_size >= (size_t)NEED_A;

    detect_kernel<<<dim3(1), dim3(256), 0, stream>>>(
        (const unsigned int*)fv, (const unsigned int*)maskp, mwords, flags);
    // feat + featT in one pass (featT only when workspace allows)
    build_feat_kernel<<<dim3(8, 32), dim3(256), 0, stream>>>(
        fv, x_idx, maskp, flags, xstride, mstride, feat, bigws ? featT : nullptr);
    // attn_w (768 x 999) -> awT (1024 x 768), rows 999..1023 zero
    transpose_kernel<1><<<dim3(32, 24, 1), dim3(256), 0, stream>>>(
        attn_w, awT, flags, 768, 1024, 768, 999, 999, 768, 0, 0);
    build_wc_kernel<<<dim3(768), dim3(256), 0, stream>>>(
        cls_w, cls_b, reg_w, reg_b, flags, wcT, biasc);

    // GEMM1: logits = feat @ attn_w  (M=32000, N=1024 padded, K=768)
    // TM=64/TN=256, XCD-grouped m-tiles: 2000 live blocks, ~3 blocks/CU
    gemm_kernel<OUT_F16, false, false, 64, 256, 2><<<dim3(2048), dim3(256), 0, stream>>>(
        feat, nullptr, 768, awT, 768, logits, 1024, 32000, 1024, 768, 0, 0, 0,
        nullptr, nullptr, flags);
    softmax_kernel<<<dim3(1000, 32), dim3(256), 0, stream>>>(logits, attn_b, flags);
    // GEMM2 (batched): att_feat = S @ feat  (M=1000, N=768, K=1024 padded, 32 batches)
    if (bigws) {
        gemm_kernel<OUT_F16, false, false, 64, 256, 4><<<dim3(1536), dim3(256), 0, stream>>>(
            logits, nullptr, 1024, featT, 1024, attf, 768, 1000, 768, 1024,
            1024000L, 786432L, 768000L, nullptr, nullptr, flags);
    } else {
        gemm_kernel<OUT_F16, false, true, 128, 128, 0><<<dim3(6, 8, 32), dim3(256), 0, stream>>>(
            logits, nullptr, 1024, feat, 768, attf, 768, 1000, 768, 1000,
            1024000L, 768000L, 768000L, nullptr, nullptr, flags);
    }
    // GEMM3: out = [att_feat | feat] @ Wc, fused epilogue; TM=64 -> 500 blocks
    gemm_kernel<OUT_FINAL, true, false, 64, 128, 0><<<dim3(1, 500, 1), dim3(256), 0, stream>>>(
        attf, feat, 768, wcT, 1536, d_out, 77, 32000, 75, 1536, 0, 0, 0,
        biasc, anchors, flags);
}

// Round 7
// 416.707 us; speedup vs baseline: 1.1250x; 1.1250x over previous
//
#include <hip/hip_runtime.h>
#include <hip/hip_bf16.h>

typedef _Float16 f16;
typedef _Float16 f16x4 __attribute__((ext_vector_type(4)));
typedef _Float16 f16x8 __attribute__((ext_vector_type(8)));
typedef float    f32x4 __attribute__((ext_vector_type(4)));

static __device__ __forceinline__ float bf2f(__hip_bfloat16 x) { return __bfloat162float(x); }
// dual-dtype float load/store: f32flag=1 -> float*, else bf16*
static __device__ __forceinline__ float ldf(const void* p, long i, int f32flag) {
    return f32flag ? ((const float*)p)[i] : bf2f(((const __hip_bfloat16*)p)[i]);
}
static __device__ __forceinline__ void stf(void* p, long i, int f32flag, float v) {
    if (f32flag) ((float*)p)[i] = v;
    else ((__hip_bfloat16*)p)[i] = __float2bfloat16(v);
}
// async global->LDS, 16B per lane; LDS dest is wave-uniform base + lane*16
static __device__ __forceinline__ void gl2lds16(const f16* g, f16* l) {
    __builtin_amdgcn_global_load_lds(
        (const __attribute__((address_space(1))) unsigned int*)(const void*)g,
        (__attribute__((address_space(3))) unsigned int*)(void*)l, 16, 0, 0);
}

// ---------------- workspace layout (bytes) ----------------
#define OFF_LOGITS 0L                               // S/logits: 32000 x 1024 f16
#define SZ_LOGITS  (32000L * 1024 * 2)
#define OFF_FEAT   (OFF_LOGITS + SZ_LOGITS)         // feat: 32000 x 768 f16
#define SZ_FEAT    (32000L * 768 * 2)
#define OFF_ATTF   (OFF_FEAT + SZ_FEAT)             // att_feat: 32000 x 768 f16
#define SZ_ATTF    (32000L * 768 * 2)
#define OFF_AWT    (OFF_ATTF + SZ_ATTF)             // attn_w^T: 1024 x 768 f16 (rows>=999 zero)
#define SZ_AWT     (1024L * 768 * 2)
#define OFF_WCT    (OFF_AWT + SZ_AWT)               // Wc^T: 128 x 1536 f16 (rows>=75 zero)
#define SZ_WCT     (128L * 1536 * 2)
#define OFF_BIAS   (OFF_WCT + SZ_WCT)               // f32[75] (padded 512)
#define OFF_FLAG   (OFF_BIAS + 512)                 // int flags[2]
#define OFF_FEATT  (OFF_FLAG + 64)                  // feat^T per batch: 32 x 768 x 1024 f16
#define SZ_FEATT   (32L * 768 * 1024 * 2)
#define NEED_A     (OFF_FEATT + SZ_FEATT)           // ~216 MB

// ---------------- detection (cheap sampling) ----------------
// flags[0]: 0=int32, 1=int8/bool, 2=bf16, 3=int64, 4=f32   flags[1]: 1=f32 floats, 0=bf16 floats
__global__ void detect_kernel(const unsigned int* __restrict__ fv,
                              const unsigned int* __restrict__ m,
                              int mwords, int* __restrict__ flags)
{
    __shared__ int cnt, bits;
    int t = threadIdx.x;
    if (t == 0) { cnt = 0; bits = 0; }
    __syncthreads();
    int c = 0;
    for (int k = t; k < 2048; k += 256) {
        unsigned int w = fv[k];
        unsigned int h0 = w & 0xffffu, h1 = w >> 16;
        unsigned int e0 = (h0 >> 7) & 0xffu, e1 = (h1 >> 7) & 0xffu;
        c += (h0 == 0u || (e0 >= 100u && e0 <= 135u)) ? 1 : 0;
        c += (h1 == 0u || (e1 >= 100u && e1 <= 135u)) ? 1 : 0;
    }
    atomicAdd(&cnt, c);
    int lb = 0;
    for (int k = t; k < mwords; k += 256) {
        unsigned int w = m[k];
        if (w > 1u) lb |= 1;                        // some word not in {0,1}
        if ((k & 1) && w != 0u) lb |= 2;            // odd word nonzero
        unsigned int lo = w & 0xffffu, hi = w >> 16;
        if (!((lo == 0u || lo == 0x3f80u) && (hi == 0u || hi == 0x3f80u))) lb |= 4;
        if (lo == 0x3f80u) lb |= 8;
    }
    if (lb) atomicOr(&bits, lb);
    __syncthreads();
    if (t == 0) {
        int b = bits, f;
        if (!(b & 1))      f = (b & 2) ? 0 : 3;     // words all {0,1}: int32 vs int64
        else if (!(b & 4)) f = (b & 8) ? 2 : 4;     // {0,0x3f80} halves: bf16 vs f32
        else               f = 1;                    // raw bytes
        flags[0] = f;
        flags[1] = (cnt < 3900) ? 1 : 0;            // bf16 ~4096 hits, f32 ~2335
    }
}

// ---------------- gather: build feat via LDS-staged fv slab ----------------
// grid (16 n-chunks of 63, 32 batches) = 512 blocks (2/CU)
__global__ __launch_bounds__(256) void build_feat_kernel(
    const void* __restrict__ fv, const int* __restrict__ x_idx,
    const void* __restrict__ maskp, const int* __restrict__ flags,
    int xstride, int mstride, f16* __restrict__ feat)
{
    __shared__ f16 sfv[15360];                      // [(c*12+h)*20 + x]
    __shared__ int sx[756];                         // [n_local*12 + h]
    __shared__ unsigned char sm[756];
    int b = blockIdx.y, n0 = blockIdx.x * 63;
    int rows = min(63, 1000 - n0);
    int t = threadIdx.x;
    int isf = flags[1], fm = flags[0];
    for (int k = t; k < 15360; k += 256)
        sfv[k] = (f16)ldf(fv, (long)b * 15360 + k, isf);
    for (int k = t; k < rows * 12; k += 256) {
        int n = k / 12, h = k - n * 12;
        sx[k] = x_idx[(long)(n0 + n) * xstride + h];
        long mb = (long)(n0 + n) * mstride + h;
        int mv;
        if (fm == 0)      mv = ((const int*)maskp)[mb] != 0;
        else if (fm == 1) mv = ((const unsigned char*)maskp)[mb] != 0;
        else if (fm == 2) mv = ((const unsigned short*)maskp)[mb] != 0;
        else if (fm == 3) mv = ((const int*)maskp)[mb * 2] != 0;
        else              mv = ((const unsigned int*)maskp)[mb] != 0;
        sm[k] = (unsigned char)mv;
    }
    __syncthreads();
    for (int q = t; q < rows * 192; q += 256) {
        int n = q / 192, r = q - n * 192;
        int e0 = r * 4;
        f16x4 v;
        #pragma unroll
        for (int j = 0; j < 4; j++) {
            int e = e0 + j;
            int h = e % 12;
            int kk = n * 12 + h;
            v[j] = sm[kk] ? (f16)0.f : sfv[e * 20 + sx[kk]];
        }
        *(f16x4*)(feat + ((long)(b * 1000 + n0 + n)) * 768 + e0) = v;
    }
}

// ---------------- transpose into f16; SRC=1: dual-float input, SRC=0: f16 input ----------------
template<int SRC>
__global__ __launch_bounds__(256) void transpose_kernel(
    const void* __restrict__ inp, f16* __restrict__ out, const int* __restrict__ flags,
    int R, int C, int inR, int inC, int ldin, int ldout, long sIn, long sOut)
{
    __shared__ f16 tile[32][33];
    int isf = SRC ? flags[1] : 0;
    int c0 = blockIdx.x * 32, r0 = blockIdx.y * 32;
    int tx = threadIdx.x & 31, ty = threadIdx.x >> 5;
    #pragma unroll
    for (int i = ty; i < 32; i += 8) {
        int r = r0 + i, c = c0 + tx;
        float v = 0.f;
        if (r < inR && c < inC) {
            long idx = (long)blockIdx.z * sIn + (long)r * ldin + c;
            v = SRC ? ldf(inp, idx, isf) : (float)((const f16*)inp)[idx];
        }
        tile[i][tx] = (f16)v;
    }
    __syncthreads();
    #pragma unroll
    for (int i = ty; i < 32; i += 8) {
        int oc = c0 + i, orw = r0 + tx;
        if (oc < C && orw < R)
            out[(long)blockIdx.z * sOut + (long)oc * ldout + orw] = tile[tx][i];
    }
}

// ---------------- combined classifier/regressor weights (128 rows, zero-padded) ----------------
__global__ __launch_bounds__(256) void build_wc_kernel(
    const void* __restrict__ cls_w, const void* __restrict__ cls_b,
    const void* __restrict__ reg_w, const void* __restrict__ reg_b,
    const int* __restrict__ flags, f16* __restrict__ wcT, float* __restrict__ biasc)
{
    int isf = flags[1];
    int idx = blockIdx.x * 256 + threadIdx.x;       // 128*1536 = 196608
    if (idx < 128 * 1536) {
        int c = idx / 1536, k = idx - c * 1536;
        float v = 0.f;
        if (c < 2)       v = ldf(cls_w, (long)k * 2 + c, isf);
        else if (c < 75) v = ldf(reg_w, (long)k * 73 + (c - 2), isf);
        wcT[idx] = (f16)v;                           // wcT[c][k], ld 1536
    }
    if (idx < 75)
        biasc[idx] = (idx < 2) ? ldf(cls_b, idx, isf) : ldf(reg_b, idx - 2, isf);
}

// ---------------- softmax over 999 + shifted scatter (in place, register-resident) ----------------
__global__ __launch_bounds__(256) void softmax_kernel(
    f16* __restrict__ buf, const void* __restrict__ attn_b, const int* __restrict__ flags)
{
    int i = blockIdx.x, b = blockIdx.y;
    f16* row = buf + ((long)(b * 1000 + i)) * 1024;
    __shared__ float red[8];
    int isf = flags[1];
    int t = threadIdx.x;
    int k0 = t * 4;
    f16x4 rv = *(const f16x4*)(row + k0);            // all reads before any write
    float v[4];
    float lmax = -3.4e38f;
    #pragma unroll
    for (int j = 0; j < 4; j++) {
        int k = k0 + j;
        float x = (k < 999) ? (float)rv[j] + ldf(attn_b, k, isf) : -3.4e38f;
        v[j] = x;
        lmax = fmaxf(lmax, x);
    }
    #pragma unroll
    for (int o = 32; o > 0; o >>= 1) lmax = fmaxf(lmax, __shfl_down(lmax, o, 64));
    if ((t & 63) == 0) red[t >> 6] = lmax;
    __syncthreads();
    float gmax = fmaxf(fmaxf(red[0], red[1]), fmaxf(red[2], red[3]));
    float lsum = 0.f;
    #pragma unroll
    for (int j = 0; j < 4; j++) {
        int k = k0 + j;
        float e = (k < 999) ? __expf(v[j] - gmax) : 0.f;
        v[j] = e;
        lsum += e;
    }
    #pragma unroll
    for (int o = 32; o > 0; o >>= 1) lsum += __shfl_down(lsum, o, 64);
    if ((t & 63) == 0) red[4 + (t >> 6)] = lsum;
    __syncthreads();
    float inv = 1.f / (red[4] + red[5] + red[6] + red[7]);
    #pragma unroll
    for (int j = 0; j < 4; j++) {
        int k = k0 + j;
        if (k < 999) row[k + (k >= i ? 1 : 0)] = (f16)(v[j] * inv);
    }
    if (t == 0) row[i] = (f16)0.f;                   // zero diagonal
}

// ---------------- MFMA GEMM ----------------
// non-BKM: unguarded global_load_lds(16B) staging into XOR-swizzled unpadded LDS.
// TM in {64,128}, TN in {128,256}.
// SWZ: 0 none; 2 GEMM1 m-group->XCD (grid 2048 flat, TM=64);
//      4 GEMM2 batch->XCD (grid 1536 flat, TM=64).
enum { OUT_F16 = 0, OUT_FINAL = 1 };

template<int MODE, bool CAT, bool BKM, int TM, int TN, int SWZ>
__global__ __launch_bounds__(256, 2) void gemm_kernel(
    const f16* __restrict__ A, const f16* __restrict__ A2, int lda,
    const f16* __restrict__ Bt, int ldb,
    void* __restrict__ Cout, int ldc,
    int M, int Nc, int K,
    long sA, long sB, long sC,
    const float* __restrict__ bias, const void* __restrict__ anchors,
    const int* __restrict__ flags)
{
    int t = threadIdx.x;
    int bx, by, bz;
    if constexpr (SWZ == 2) {          // grid 2048 flat: 500 m-groups x 4 n-blocks
        int bid = blockIdx.x;
        int xcd = bid & 7, s = bid >> 3;             // s in [0,256)
        int g = xcd + 8 * (s >> 2);                  // XCD owns groups g == xcd (mod 8)
        if (g >= 500) return;                        // 48 idle blocks
        by = g; bx = s & 3; bz = 0;
    } else if constexpr (SWZ == 4) {   // grid 1536 flat: 8 XCD x 4 batches x (16m x 3n)
        int bid = blockIdx.x;
        int xcd = bid & 7, s = bid >> 3;             // s in [0,192)
        bz = xcd * 4 + s / 48;
        int wv = s % 48;
        by = wv / 3; bx = wv - by * 3;
    } else { bx = blockIdx.x; by = blockIdx.y; bz = blockIdx.z; }

    int m0 = by * TM, n0 = bx * TN;
    int z = bz;
    A  += (long)z * sA;
    if (CAT) A2 += (long)z * sA;
    Bt += (long)z * sB;
    int w = t >> 6, lane = t & 63;
    constexpr int NJ = (TM == 128 && TN == 256) ? 8 : ((TN == 256) ? 4 : ((TM == 128) ? 4 : 2));
    int wm = (TM == 128) ? (w & 1) * 64 : 0;
    int wn;
    if constexpr (TM == 128 && TN == 256) wn = (w >> 1) * 128;
    else if constexpr (TN == 256)         wn = w * 64;
    else if constexpr (TM == 128)         wn = (w >> 1) * 64;
    else                                  wn = w * 32;

    int lr = lane & 15, lq = lane >> 4;

    const f32x4 zero4 = {0.f, 0.f, 0.f, 0.f};
    f32x4 acc[4][NJ];
    #pragma unroll
    for (int i = 0; i < 4; i++)
        #pragma unroll
        for (int j = 0; j < NJ; j++) acc[i][j] = zero4;

    if constexpr (!BKM) {
        constexpr int AI = TM / 64;                  // A staging iterations
        constexpr int BI = TN / 64;                  // B staging iterations
        __shared__ __align__(16) f16 As[TM * 32];
        __shared__ __align__(16) f16 Bs[TN * 32];
        long aoff[AI], boff[BI];
        f16 *lA[AI], *lB[BI];
        #pragma unroll
        for (int i = 0; i < AI; i++) {
            int q = t + i * 256;
            int row = q >> 2, slot = q & 3;
            int c = slot ^ ((row >> 1) & 3);
            aoff[i] = (long)(m0 + row) * lda + c * 8;
            lA[i] = &As[(i * 256 + w * 64) * 8];     // wave-uniform base
        }
        #pragma unroll
        for (int i = 0; i < BI; i++) {
            int q = t + i * 256;
            int row = q >> 2, slot = q & 3;
            int c = slot ^ ((row >> 1) & 3);
            boff[i] = (long)(n0 + row) * ldb + c * 8;
            lB[i] = &Bs[(i * 256 + w * 64) * 8];
        }
        for (int k0 = 0; k0 < K; k0 += 32) {
            const f16* Ak = A; int kk = k0;
            if (CAT && k0 >= 768) { Ak = A2; kk = k0 - 768; }
            __syncthreads();
            #pragma unroll
            for (int i = 0; i < AI; i++) gl2lds16(Ak + aoff[i] + kk, lA[i]);
            #pragma unroll
            for (int i = 0; i < BI; i++) gl2lds16(Bt + boff[i] + k0, lB[i]);
            __syncthreads();                         // drains vmcnt before barrier
            f16x8 af[4], bfr[NJ];
            #pragma unroll
            for (int i = 0; i < 4; i++) {
                int r = wm + i * 16 + lr;
                af[i] = *(const f16x8*)&As[r * 32 + (lq ^ ((r >> 1) & 3)) * 8];
            }
            #pragma unroll
            for (int j = 0; j < NJ; j++) {
                int r = wn + j * 16 + lr;
                bfr[j] = *(const f16x8*)&Bs[r * 32 + (lq ^ ((r >> 1) & 3)) * 8];
            }
            #pragma unroll
            for (int i = 0; i < 4; i++)
                #pragma unroll
                for (int j = 0; j < NJ; j++)
                    acc[i][j] = __builtin_amdgcn_mfma_f32_16x16x32_f16(af[i], bfr[j], acc[i][j], 0, 0, 0);
        }
    } else {
        __shared__ __align__(16) f16 As[128 * 40];
        __shared__ __align__(16) f16 Bs[32 * 132];
        const f16x8 zero8 = {(f16)0, (f16)0, (f16)0, (f16)0, (f16)0, (f16)0, (f16)0, (f16)0};
        const f16x4 zero4h = {(f16)0, (f16)0, (f16)0, (f16)0};
        for (int k0 = 0; k0 < K; k0 += 32) {
            __syncthreads();
            #pragma unroll
            for (int i = 0; i < 2; i++) {
                int q = t + i * 256;
                { int row = q >> 2, kc = (q & 3) * 8;
                  f16x8 av = zero8;
                  if ((m0 + row) < M && (k0 + kc) < K)
                      av = *(const f16x8*)(A + (long)(m0 + row) * lda + k0 + kc);
                  *(f16x8*)&As[row * 40 + kc] = av; }
                { int kr = q >> 4, nc = (q & 15) * 8;
                  f16x4 b0 = zero4h, b1 = zero4h;
                  if ((k0 + kr) < K && (n0 + nc) < Nc) {
                      const f16* p = Bt + (long)(k0 + kr) * ldb + n0 + nc;
                      b0 = *(const f16x4*)p;
                      b1 = *(const f16x4*)(p + 4);
                  }
                  *(f16x4*)&Bs[kr * 132 + nc]     = b0;
                  *(f16x4*)&Bs[kr * 132 + nc + 4] = b1; }
            }
            __syncthreads();
            f16x8 af[4], bfr[NJ];
            #pragma unroll
            for (int i = 0; i < 4; i++)
                af[i] = *(const f16x8*)&As[(wm + i * 16 + lr) * 40 + lq * 8];
            #pragma unroll
            for (int j = 0; j < NJ; j++)
                #pragma unroll
                for (int jj = 0; jj < 8; jj++)
                    bfr[j][jj] = Bs[(lq * 8 + jj) * 132 + wn + j * 16 + lr];
            #pragma unroll
            for (int i = 0; i < 4; i++)
                #pragma unroll
                for (int j = 0; j < NJ; j++)
                    acc[i][j] = __builtin_amdgcn_mfma_f32_16x16x32_f16(af[i], bfr[j], acc[i][j], 0, 0, 0);
        }
    }

    int isf = (MODE == OUT_FINAL) ? flags[1] : 0;
    #pragma unroll
    for (int i = 0; i < 4; i++) {
        #pragma unroll
        for (int j = 0; j < NJ; j++) {
            #pragma unroll
            for (int r = 0; r < 4; r++) {
                int gm = m0 + wm + i * 16 + lq * 4 + r;   // C/D: row = quad*4+reg
                int gn = n0 + wn + j * 16 + lr;           //      col = lane&15
                if (MODE == OUT_F16) {
                    if (gm < M && gn < Nc)
                        ((f16*)Cout)[(long)z * sC + (long)gm * ldc + gn] = (f16)acc[i][j][r];
                } else {
                    if (gn < Nc) {                         // Nc=75 real cols
                        float v = acc[i][j][r] + bias[gn];
                        int oc = (gn < 2) ? gn : gn + 2;   // skip anchor cols 2,3
                        if (gn >= 2) v += ldf(anchors, (long)(gm % 1000) * 77 + oc, isf);
                        stf(Cout, (long)gm * 77 + oc, isf, v);
                    } else if (gn < 77) {                  // wasted lanes fill anchor cols 2,3
                        int oc = gn - 73;                  // 75->2, 76->3
                        stf(Cout, (long)gm * 77 + oc, isf,
                            ldf(anchors, (long)(gm % 1000) * 77 + oc, isf));
                    }
                }
            }
        }
    }
}

extern "C" void kernel_launch(void* const* d_in, const int* in_sizes, int n_in,
                              void* d_out, int out_size, void* d_ws, size_t ws_size,
                              hipStream_t stream)
{
    const void* fv      = d_in[0];
    const void* attn_w  = d_in[1];
    const void* attn_b  = d_in[2];
    const void* cls_w   = d_in[3];
    const void* cls_b   = d_in[4];
    const void* reg_w   = d_in[5];
    const void* reg_b   = d_in[6];
    const void* anchors = d_in[7];
    const int*  x_idx   = (const int*)d_in[10];
    const void* maskp   = d_in[11];
    int xstride = (in_sizes[10] < 768000) ? 12 : 768;   // un-broadcast fallback
    int mstride = (in_sizes[11] < 768000) ? 12 : 768;
    int mwords  = in_sizes[11] / 4;                      // int8 worst case, stay in bounds
    if (mwords > 4096) mwords = 4096;

    char* ws = (char*)d_ws;
    f16*   logits = (f16*)(ws + OFF_LOGITS);
    f16*   feat   = (f16*)(ws + OFF_FEAT);
    f16*   attf   = (f16*)(ws + OFF_ATTF);
    f16*   awT    = (f16*)(ws + OFF_AWT);
    f16*   wcT    = (f16*)(ws + OFF_WCT);
    float* biasc  = (float*)(ws + OFF_BIAS);
    int*   flags  = (int*)(ws + OFF_FLAG);
    f16*   featT  = (f16*)(ws + OFF_FEATT);
    bool bigws = ws_size >= (size_t)NEED_A;

    detect_kernel<<<dim3(1), dim3(256), 0, stream>>>(
        (const unsigned int*)fv, (const unsigned int*)maskp, mwords, flags);
    build_feat_kernel<<<dim3(16, 32), dim3(256), 0, stream>>>(
        fv, x_idx, maskp, flags, xstride, mstride, feat);
    // attn_w (768 x 999) -> awT (1024 x 768), rows 999..1023 zero
    transpose_kernel<1><<<dim3(32, 24, 1), dim3(256), 0, stream>>>(
        attn_w, awT, flags, 768, 1024, 768, 999, 999, 768, 0, 0);
    build_wc_kernel<<<dim3(768), dim3(256), 0, stream>>>(
        cls_w, cls_b, reg_w, reg_b, flags, wcT, biasc);

    // GEMM1: logits = feat @ attn_w  (M=32000, N=1024 padded, K=768)
    gemm_kernel<OUT_F16, false, false, 64, 256, 2><<<dim3(2048), dim3(256), 0, stream>>>(
        feat, nullptr, 768, awT, 768, logits, 1024, 32000, 1024, 768, 0, 0, 0,
        nullptr, nullptr, flags);
    softmax_kernel<<<dim3(1000, 32), dim3(256), 0, stream>>>(logits, attn_b, flags);
    // GEMM2 (batched): att_feat = S @ feat  (M=1000, N=768, K=1024 padded, 32 batches)
    if (bigws) {
        // feat (1000 x 768 per batch) -> featT (768 x 1024 per batch), rows>=1000 zero
        transpose_kernel<0><<<dim3(24, 32, 32), dim3(256), 0, stream>>>(
            feat, featT, flags, 1024, 768, 1000, 768, 768, 1024, 768000L, 786432L);
        gemm_kernel<OUT_F16, false, false, 64, 256, 4><<<dim3(1536), dim3(256), 0, stream>>>(
            logits, nullptr, 1024, featT, 1024, attf, 768, 1000, 768, 1024,
            1024000L, 786432L, 768000L, nullptr, nullptr, flags);
    } else {
        gemm_kernel<OUT_F16, false, true, 128, 128, 0><<<dim3(6, 8, 32), dim3(256), 0, stream>>>(
            logits, nullptr, 1024, feat, 768, attf, 768, 1000, 768, 1000,
            1024000L, 768000L, 768000L, nullptr, nullptr, flags);
    }
    // GEMM3: out = [att_feat | feat] @ Wc, fused epilogue; TM=64 -> 500 blocks
    gemm_kernel<OUT_FINAL, true, false, 64, 128, 0><<<dim3(1, 500, 1), dim3(256), 0, stream>>>(
        attf, feat, 768, wcT, 1536, d_out, 77, 32000, 75, 1536, 0, 0, 0,
        biasc, anchors, flags);
}

// Round 8
// 381.810 us; speedup vs baseline: 1.2278x; 1.0914x over previous
//
#include <hip/hip_runtime.h>
#include <hip/hip_bf16.h>

typedef _Float16 f16;
typedef _Float16 f16x4 __attribute__((ext_vector_type(4)));
typedef _Float16 f16x8 __attribute__((ext_vector_type(8)));
typedef float    f32x4 __attribute__((ext_vector_type(4)));

static __device__ __forceinline__ float bf2f(__hip_bfloat16 x) { return __bfloat162float(x); }
// dual-dtype float load/store: f32flag=1 -> float*, else bf16*
static __device__ __forceinline__ float ldf(const void* p, long i, int f32flag) {
    return f32flag ? ((const float*)p)[i] : bf2f(((const __hip_bfloat16*)p)[i]);
}
static __device__ __forceinline__ void stf(void* p, long i, int f32flag, float v) {
    if (f32flag) ((float*)p)[i] = v;
    else ((__hip_bfloat16*)p)[i] = __float2bfloat16(v);
}
// async global->LDS, 16B per lane; LDS dest is wave-uniform base + lane*16
static __device__ __forceinline__ void gl2lds16(const f16* g, f16* l) {
    __builtin_amdgcn_global_load_lds(
        (const __attribute__((address_space(1))) unsigned int*)(const void*)g,
        (__attribute__((address_space(3))) unsigned int*)(void*)l, 16, 0, 0);
}

// ---------------- workspace layout (bytes) ----------------
#define OFF_LOGITS 0L                               // S/logits: 32000 x 1024 f16
#define SZ_LOGITS  (32000L * 1024 * 2)
#define OFF_FEAT   (OFF_LOGITS + SZ_LOGITS)         // feat: 32000 x 768 f16
#define SZ_FEAT    (32000L * 768 * 2)
#define OFF_ATTF   (OFF_FEAT + SZ_FEAT)             // att_feat: 32000 x 768 f16
#define SZ_ATTF    (32000L * 768 * 2)
#define OFF_AWT    (OFF_ATTF + SZ_ATTF)             // attn_w^T: 1024 x 768 f16 (rows>=999 zero)
#define SZ_AWT     (1024L * 768 * 2)
#define OFF_WCT    (OFF_AWT + SZ_AWT)               // Wc^T: 128 x 1536 f16 (rows>=75 zero)
#define SZ_WCT     (128L * 1536 * 2)
#define OFF_BIAS   (OFF_WCT + SZ_WCT)               // f32[75] (padded 512)
#define OFF_FLAG   (OFF_BIAS + 512)                 // int flags[2]
#define OFF_FEATT  (OFF_FLAG + 64)                  // feat^T per batch: 32 x 768 x 1024 f16
#define SZ_FEATT   (32L * 768 * 1024 * 2)
#define NEED_A     (OFF_FEATT + SZ_FEATT)           // ~216 MB

// ---------------- detection (cheap sampling) ----------------
// flags[0]: 0=int32, 1=int8/bool, 2=bf16, 3=int64, 4=f32   flags[1]: 1=f32 floats, 0=bf16 floats
__global__ void detect_kernel(const unsigned int* __restrict__ fv,
                              const unsigned int* __restrict__ m,
                              int mwords, int* __restrict__ flags)
{
    __shared__ int cnt, bits;
    int t = threadIdx.x;
    if (t == 0) { cnt = 0; bits = 0; }
    __syncthreads();
    int c = 0;
    for (int k = t; k < 2048; k += 256) {
        unsigned int w = fv[k];
        unsigned int h0 = w & 0xffffu, h1 = w >> 16;
        unsigned int e0 = (h0 >> 7) & 0xffu, e1 = (h1 >> 7) & 0xffu;
        c += (h0 == 0u || (e0 >= 100u && e0 <= 135u)) ? 1 : 0;
        c += (h1 == 0u || (e1 >= 100u && e1 <= 135u)) ? 1 : 0;
    }
    atomicAdd(&cnt, c);
    int lb = 0;
    for (int k = t; k < mwords; k += 256) {
        unsigned int w = m[k];
        if (w > 1u) lb |= 1;                        // some word not in {0,1}
        if ((k & 1) && w != 0u) lb |= 2;            // odd word nonzero
        unsigned int lo = w & 0xffffu, hi = w >> 16;
        if (!((lo == 0u || lo == 0x3f80u) && (hi == 0u || hi == 0x3f80u))) lb |= 4;
        if (lo == 0x3f80u) lb |= 8;
    }
    if (lb) atomicOr(&bits, lb);
    __syncthreads();
    if (t == 0) {
        int b = bits, f;
        if (!(b & 1))      f = (b & 2) ? 0 : 3;     // words all {0,1}: int32 vs int64
        else if (!(b & 4)) f = (b & 8) ? 2 : 4;     // {0,0x3f80} halves: bf16 vs f32
        else               f = 1;                    // raw bytes
        flags[0] = f;
        flags[1] = (cnt < 3900) ? 1 : 0;            // bf16 ~4096 hits, f32 ~2335
    }
}

// ---------------- gather: build feat via LDS-staged fv slab ----------------
// grid (16 n-chunks of 63, 32 batches) = 512 blocks (2/CU)
__global__ __launch_bounds__(256) void build_feat_kernel(
    const void* __restrict__ fv, const int* __restrict__ x_idx,
    const void* __restrict__ maskp, const int* __restrict__ flags,
    int xstride, int mstride, f16* __restrict__ feat)
{
    __shared__ f16 sfv[15360];                      // [(c*12+h)*20 + x]
    __shared__ int sx[756];                         // [n_local*12 + h]
    __shared__ unsigned char sm[756];
    int b = blockIdx.y, n0 = blockIdx.x * 63;
    int rows = min(63, 1000 - n0);
    int t = threadIdx.x;
    int isf = flags[1], fm = flags[0];
    for (int k = t; k < 15360; k += 256)
        sfv[k] = (f16)ldf(fv, (long)b * 15360 + k, isf);
    for (int k = t; k < rows * 12; k += 256) {
        int n = k / 12, h = k - n * 12;
        sx[k] = x_idx[(long)(n0 + n) * xstride + h];
        long mb = (long)(n0 + n) * mstride + h;
        int mv;
        if (fm == 0)      mv = ((const int*)maskp)[mb] != 0;
        else if (fm == 1) mv = ((const unsigned char*)maskp)[mb] != 0;
        else if (fm == 2) mv = ((const unsigned short*)maskp)[mb] != 0;
        else if (fm == 3) mv = ((const int*)maskp)[mb * 2] != 0;
        else              mv = ((const unsigned int*)maskp)[mb] != 0;
        sm[k] = (unsigned char)mv;
    }
    __syncthreads();
    for (int q = t; q < rows * 192; q += 256) {
        int n = q / 192, r = q - n * 192;
        int e0 = r * 4;
        f16x4 v;
        #pragma unroll
        for (int j = 0; j < 4; j++) {
            int e = e0 + j;
            int h = e % 12;
            int kk = n * 12 + h;
            v[j] = sm[kk] ? (f16)0.f : sfv[e * 20 + sx[kk]];
        }
        *(f16x4*)(feat + ((long)(b * 1000 + n0 + n)) * 768 + e0) = v;
    }
}

// ---------------- transpose into f16; SRC=1: dual-float input, SRC=0: f16 input ----------------
template<int SRC>
__global__ __launch_bounds__(256) void transpose_kernel(
    const void* __restrict__ inp, f16* __restrict__ out, const int* __restrict__ flags,
    int R, int C, int inR, int inC, int ldin, int ldout, long sIn, long sOut)
{
    __shared__ f16 tile[32][33];
    int isf = SRC ? flags[1] : 0;
    int c0 = blockIdx.x * 32, r0 = blockIdx.y * 32;
    int tx = threadIdx.x & 31, ty = threadIdx.x >> 5;
    #pragma unroll
    for (int i = ty; i < 32; i += 8) {
        int r = r0 + i, c = c0 + tx;
        float v = 0.f;
        if (r < inR && c < inC) {
            long idx = (long)blockIdx.z * sIn + (long)r * ldin + c;
            v = SRC ? ldf(inp, idx, isf) : (float)((const f16*)inp)[idx];
        }
        tile[i][tx] = (f16)v;
    }
    __syncthreads();
    #pragma unroll
    for (int i = ty; i < 32; i += 8) {
        int oc = c0 + i, orw = r0 + tx;
        if (oc < C && orw < R)
            out[(long)blockIdx.z * sOut + (long)oc * ldout + orw] = tile[tx][i];
    }
}

// ---------------- combined classifier/regressor weights (128 rows, zero-padded) ----------------
__global__ __launch_bounds__(256) void build_wc_kernel(
    const void* __restrict__ cls_w, const void* __restrict__ cls_b,
    const void* __restrict__ reg_w, const void* __restrict__ reg_b,
    const int* __restrict__ flags, f16* __restrict__ wcT, float* __restrict__ biasc)
{
    int isf = flags[1];
    int idx = blockIdx.x * 256 + threadIdx.x;       // 128*1536 = 196608
    if (idx < 128 * 1536) {
        int c = idx / 1536, k = idx - c * 1536;
        float v = 0.f;
        if (c < 2)       v = ldf(cls_w, (long)k * 2 + c, isf);
        else if (c < 75) v = ldf(reg_w, (long)k * 73 + (c - 2), isf);
        wcT[idx] = (f16)v;                           // wcT[c][k], ld 1536
    }
    if (idx < 75)
        biasc[idx] = (idx < 2) ? ldf(cls_b, idx, isf) : ldf(reg_b, idx - 2, isf);
}

// ---------------- softmax over 999 + shifted scatter (in place, register-resident) ----------------
__global__ __launch_bounds__(256) void softmax_kernel(
    f16* __restrict__ buf, const void* __restrict__ attn_b, const int* __restrict__ flags)
{
    int i = blockIdx.x, b = blockIdx.y;
    f16* row = buf + ((long)(b * 1000 + i)) * 1024;
    __shared__ float red[8];
    int isf = flags[1];
    int t = threadIdx.x;
    int k0 = t * 4;
    f16x4 rv = *(const f16x4*)(row + k0);            // all reads before any write
    float v[4];
    float lmax = -3.4e38f;
    #pragma unroll
    for (int j = 0; j < 4; j++) {
        int k = k0 + j;
        float x = (k < 999) ? (float)rv[j] + ldf(attn_b, k, isf) : -3.4e38f;
        v[j] = x;
        lmax = fmaxf(lmax, x);
    }
    #pragma unroll
    for (int o = 32; o > 0; o >>= 1) lmax = fmaxf(lmax, __shfl_down(lmax, o, 64));
    if ((t & 63) == 0) red[t >> 6] = lmax;
    __syncthreads();
    float gmax = fmaxf(fmaxf(red[0], red[1]), fmaxf(red[2], red[3]));
    float lsum = 0.f;
    #pragma unroll
    for (int j = 0; j < 4; j++) {
        int k = k0 + j;
        float e = (k < 999) ? __expf(v[j] - gmax) : 0.f;
        v[j] = e;
        lsum += e;
    }
    #pragma unroll
    for (int o = 32; o > 0; o >>= 1) lsum += __shfl_down(lsum, o, 64);
    if ((t & 63) == 0) red[4 + (t >> 6)] = lsum;
    __syncthreads();
    float inv = 1.f / (red[4] + red[5] + red[6] + red[7]);
    #pragma unroll
    for (int j = 0; j < 4; j++) {
        int k = k0 + j;
        if (k < 999) row[k + (k >= i ? 1 : 0)] = (f16)(v[j] * inv);
    }
    if (t == 0) row[i] = (f16)0.f;                   // zero diagonal
}

// ---------------- MFMA GEMM ----------------
// non-BKM: BK=64 K-chunks, unguarded global_load_lds(16B) into XOR-swizzled LDS
//   (row stride 64 elems = full 32 banks; slot = chunk ^ (row&7) -> 2-way reads, free).
//   64 MFMA per wave per barrier (2x vs BK=32) to amortize the vmcnt(0) drain.
// SWZ: 0 none; 2 GEMM1 m-group->XCD (grid ngroups*4 ceil 8); 3 GEMM2 batch->XCD (grid 768).
enum { OUT_F16 = 0, OUT_FINAL = 1 };

template<int MODE, bool CAT, bool BKM, int TM, int TN, int SWZ>
__global__ __launch_bounds__(256, 2) void gemm_kernel(
    const f16* __restrict__ A, const f16* __restrict__ A2, int lda,
    const f16* __restrict__ Bt, int ldb,
    void* __restrict__ Cout, int ldc,
    int M, int Nc, int K,
    long sA, long sB, long sC,
    const float* __restrict__ bias, const void* __restrict__ anchors,
    const int* __restrict__ flags)
{
    int t = threadIdx.x;
    int bx, by, bz;
    if constexpr (SWZ == 2) {          // flat grid: ngroups m-groups x 4 n-blocks
        int bid = blockIdx.x;
        int xcd = bid & 7, s = bid >> 3;
        int g = xcd + 8 * (s >> 2);                  // XCD owns groups g == xcd (mod 8)
        if (g >= (M + TM - 1) / TM) return;
        by = g; bx = s & 3; bz = 0;
    } else if constexpr (SWZ == 3) {   // grid 768 flat: 8 XCD x 4 batches x (8m x 3n)
        int bid = blockIdx.x;
        int xcd = bid & 7, s = bid >> 3;             // s in [0,96)
        bz = xcd * 4 + s / 24;
        int wv = s % 24;
        by = wv / 3; bx = wv - by * 3;
    } else { bx = blockIdx.x; by = blockIdx.y; bz = blockIdx.z; }

    int m0 = by * TM, n0 = bx * TN;
    int z = bz;
    A  += (long)z * sA;
    if (CAT) A2 += (long)z * sA;
    Bt += (long)z * sB;
    int w = t >> 6, lane = t & 63;
    constexpr int NJ = (TM == 128 && TN == 256) ? 8 : ((TN == 256) ? 4 : ((TM == 128) ? 4 : 2));
    int wm = (TM == 128) ? (w & 1) * 64 : 0;
    int wn;
    if constexpr (TM == 128 && TN == 256) wn = (w >> 1) * 128;
    else if constexpr (TN == 256)         wn = w * 64;
    else if constexpr (TM == 128)         wn = (w >> 1) * 64;
    else                                  wn = w * 32;

    int lr = lane & 15, lq = lane >> 4;

    const f32x4 zero4 = {0.f, 0.f, 0.f, 0.f};
    f32x4 acc[4][NJ];
    #pragma unroll
    for (int i = 0; i < 4; i++)
        #pragma unroll
        for (int j = 0; j < NJ; j++) acc[i][j] = zero4;

    if constexpr (!BKM) {
        constexpr int AI = TM / 32;                  // staging iters (2048 elems each)
        constexpr int BI = TN / 32;
        __shared__ __align__(16) f16 As[TM * 64];
        __shared__ __align__(16) f16 Bs[TN * 64];
        // staging: q = t + i*256; row = q>>3 (8 chunks/row), slot = q&7,
        // global chunk c = slot ^ (row&7). rows advance 32 per i (32%8==0 -> c i-invariant)
        int row0 = t >> 3, slot = t & 7;
        int csw = slot ^ (row0 & 7);
        long aoffB = (long)(m0 + row0) * lda + csw * 8;
        long boffB = (long)(n0 + row0) * ldb + csw * 8;
        for (int k0 = 0; k0 < K; k0 += 64) {
            const f16* Ak = A; int kk = k0;
            if (CAT && k0 >= 768) { Ak = A2; kk = k0 - 768; }
            __syncthreads();
            #pragma unroll
            for (int i = 0; i < AI; i++)
                gl2lds16(Ak + aoffB + (long)i * 32 * lda + kk, &As[(i * 256 + w * 64) * 8]);
            #pragma unroll
            for (int i = 0; i < BI; i++)
                gl2lds16(Bt + boffB + (long)i * 32 * ldb + k0, &Bs[(i * 256 + w * 64) * 8]);
            __syncthreads();                         // drains vmcnt before barrier
            #pragma unroll
            for (int ks = 0; ks < 2; ks++) {
                f16x8 af[4], bfr[NJ];
                #pragma unroll
                for (int i = 0; i < 4; i++) {
                    int r = wm + i * 16 + lr;
                    int cc = (lq + ks * 4) ^ (r & 7);
                    af[i] = *(const f16x8*)&As[r * 64 + cc * 8];
                }
                #pragma unroll
                for (int j = 0; j < NJ; j++) {
                    int r = wn + j * 16 + lr;
                    int cc = (lq + ks * 4) ^ (r & 7);
                    bfr[j] = *(const f16x8*)&Bs[r * 64 + cc * 8];
                }
                #pragma unroll
                for (int i = 0; i < 4; i++)
                    #pragma unroll
                    for (int j = 0; j < NJ; j++)
                        acc[i][j] = __builtin_amdgcn_mfma_f32_16x16x32_f16(af[i], bfr[j], acc[i][j], 0, 0, 0);
            }
        }
    } else {
        __shared__ __align__(16) f16 As[128 * 40];
        __shared__ __align__(16) f16 Bs[32 * 132];
        const f16x8 zero8 = {(f16)0, (f16)0, (f16)0, (f16)0, (f16)0, (f16)0, (f16)0, (f16)0};
        const f16x4 zero4h = {(f16)0, (f16)0, (f16)0, (f16)0};
        for (int k0 = 0; k0 < K; k0 += 32) {
            __syncthreads();
            #pragma unroll
            for (int i = 0; i < 2; i++) {
                int q = t + i * 256;
                { int row = q >> 2, kc = (q & 3) * 8;
                  f16x8 av = zero8;
                  if ((m0 + row) < M && (k0 + kc) < K)
                      av = *(const f16x8*)(A + (long)(m0 + row) * lda + k0 + kc);
                  *(f16x8*)&As[row * 40 + kc] = av; }
                { int kr = q >> 4, nc = (q & 15) * 8;
                  f16x4 b0 = zero4h, b1 = zero4h;
                  if ((k0 + kr) < K && (n0 + nc) < Nc) {
                      const f16* p = Bt + (long)(k0 + kr) * ldb + n0 + nc;
                      b0 = *(const f16x4*)p;
                      b1 = *(const f16x4*)(p + 4);
                  }
                  *(f16x4*)&Bs[kr * 132 + nc]     = b0;
                  *(f16x4*)&Bs[kr * 132 + nc + 4] = b1; }
            }
            __syncthreads();
            f16x8 af[4], bfr[NJ];
            #pragma unroll
            for (int i = 0; i < 4; i++)
                af[i] = *(const f16x8*)&As[(wm + i * 16 + lr) * 40 + lq * 8];
            #pragma unroll
            for (int j = 0; j < NJ; j++)
                #pragma unroll
                for (int jj = 0; jj < 8; jj++)
                    bfr[j][jj] = Bs[(lq * 8 + jj) * 132 + wn + j * 16 + lr];
            #pragma unroll
            for (int i = 0; i < 4; i++)
                #pragma unroll
                for (int j = 0; j < NJ; j++)
                    acc[i][j] = __builtin_amdgcn_mfma_f32_16x16x32_f16(af[i], bfr[j], acc[i][j], 0, 0, 0);
        }
    }

    int isf = (MODE == OUT_FINAL) ? flags[1] : 0;
    #pragma unroll
    for (int i = 0; i < 4; i++) {
        #pragma unroll
        for (int j = 0; j < NJ; j++) {
            #pragma unroll
            for (int r = 0; r < 4; r++) {
                int gm = m0 + wm + i * 16 + lq * 4 + r;   // C/D: row = quad*4+reg
                int gn = n0 + wn + j * 16 + lr;           //      col = lane&15
                if (MODE == OUT_F16) {
                    if (gm < M && gn < Nc)
                        ((f16*)Cout)[(long)z * sC + (long)gm * ldc + gn] = (f16)acc[i][j][r];
                } else {
                    if (gn < Nc) {                         // Nc=75 real cols
                        float v = acc[i][j][r] + bias[gn];
                        int oc = (gn < 2) ? gn : gn + 2;   // skip anchor cols 2,3
                        if (gn >= 2) v += ldf(anchors, (long)(gm % 1000) * 77 + oc, isf);
                        stf(Cout, (long)gm * 77 + oc, isf, v);
                    } else if (gn < 77) {                  // wasted lanes fill anchor cols 2,3
                        int oc = gn - 73;                  // 75->2, 76->3
                        stf(Cout, (long)gm * 77 + oc, isf,
                            ldf(anchors, (long)(gm % 1000) * 77 + oc, isf));
                    }
                }
            }
        }
    }
}

extern "C" void kernel_launch(void* const* d_in, const int* in_sizes, int n_in,
                              void* d_out, int out_size, void* d_ws, size_t ws_size,
                              hipStream_t stream)
{
    const void* fv      = d_in[0];
    const void* attn_w  = d_in[1];
    const void* attn_b  = d_in[2];
    const void* cls_w   = d_in[3];
    const void* cls_b   = d_in[4];
    const void* reg_w   = d_in[5];
    const void* reg_b   = d_in[6];
    const void* anchors = d_in[7];
    const int*  x_idx   = (const int*)d_in[10];
    const void* maskp   = d_in[11];
    int xstride = (in_sizes[10] < 768000) ? 12 : 768;   // un-broadcast fallback
    int mstride = (in_sizes[11] < 768000) ? 12 : 768;
    int mwords  = in_sizes[11] / 4;                      // int8 worst case, stay in bounds
    if (mwords > 4096) mwords = 4096;

    char* ws = (char*)d_ws;
    f16*   logits = (f16*)(ws + OFF_LOGITS);
    f16*   feat   = (f16*)(ws + OFF_FEAT);
    f16*   attf   = (f16*)(ws + OFF_ATTF);
    f16*   awT    = (f16*)(ws + OFF_AWT);
    f16*   wcT    = (f16*)(ws + OFF_WCT);
    float* biasc  = (float*)(ws + OFF_BIAS);
    int*   flags  = (int*)(ws + OFF_FLAG);
    f16*   featT  = (f16*)(ws + OFF_FEATT);
    bool bigws = ws_size >= (size_t)NEED_A;

    detect_kernel<<<dim3(1), dim3(256), 0, stream>>>(
        (const unsigned int*)fv, (const unsigned int*)maskp, mwords, flags);
    build_feat_kernel<<<dim3(16, 32), dim3(256), 0, stream>>>(
        fv, x_idx, maskp, flags, xstride, mstride, feat);
    // attn_w (768 x 999) -> awT (1024 x 768), rows 999..1023 zero
    transpose_kernel<1><<<dim3(32, 24, 1), dim3(256), 0, stream>>>(
        attn_w, awT, flags, 768, 1024, 768, 999, 999, 768, 0, 0);
    build_wc_kernel<<<dim3(768), dim3(256), 0, stream>>>(
        cls_w, cls_b, reg_w, reg_b, flags, wcT, biasc);

    // GEMM1: logits = feat @ attn_w  (M=32000, N=1024 padded, K=768), BK=64
    // TM=128/TN=256, 250 m-groups x 4 n-blocks, m-group->XCD swizzle
    gemm_kernel<OUT_F16, false, false, 128, 256, 2><<<dim3(1024), dim3(256), 0, stream>>>(
        feat, nullptr, 768, awT, 768, logits, 1024, 32000, 1024, 768, 0, 0, 0,
        nullptr, nullptr, flags);
    softmax_kernel<<<dim3(1000, 32), dim3(256), 0, stream>>>(logits, attn_b, flags);
    // GEMM2 (batched): att_feat = S @ feat  (M=1000, N=768, K=1024 padded, 32 batches), BK=64
    if (bigws) {
        // feat (1000 x 768 per batch) -> featT (768 x 1024 per batch), rows>=1000 zero
        transpose_kernel<0><<<dim3(24, 32, 32), dim3(256), 0, stream>>>(
            feat, featT, flags, 1024, 768, 1000, 768, 768, 1024, 768000L, 786432L);
        gemm_kernel<OUT_F16, false, false, 128, 256, 3><<<dim3(768), dim3(256), 0, stream>>>(
            logits, nullptr, 1024, featT, 1024, attf, 768, 1000, 768, 1024,
            1024000L, 786432L, 768000L, nullptr, nullptr, flags);
    } else {
        gemm_kernel<OUT_F16, false, true, 128, 128, 0><<<dim3(6, 8, 32), dim3(256), 0, stream>>>(
            logits, nullptr, 1024, feat, 768, attf, 768, 1000, 768, 1000,
            1024000L, 768000L, 768000L, nullptr, nullptr, flags);
    }
    // GEMM3: out = [att_feat | feat] @ Wc, fused epilogue; TM=64/TN=128, BK=64
    gemm_kernel<OUT_FINAL, true, false, 64, 128, 0><<<dim3(1, 500, 1), dim3(256), 0, stream>>>(
        attf, feat, 768, wcT, 1536, d_out, 77, 32000, 75, 1536, 0, 0, 0,
        biasc, anchors, flags);
}

// Round 9
// 374.983 us; speedup vs baseline: 1.2501x; 1.0182x over previous
//
#include <hip/hip_runtime.h>
#include <hip/hip_bf16.h>

typedef _Float16 f16;
typedef _Float16 f16x4 __attribute__((ext_vector_type(4)));
typedef _Float16 f16x8 __attribute__((ext_vector_type(8)));
typedef float    f32x4 __attribute__((ext_vector_type(4)));

static __device__ __forceinline__ float bf2f(__hip_bfloat16 x) { return __bfloat162float(x); }
// dual-dtype float load/store: f32flag=1 -> float*, else bf16*
static __device__ __forceinline__ float ldf(const void* p, long i, int f32flag) {
    return f32flag ? ((const float*)p)[i] : bf2f(((const __hip_bfloat16*)p)[i]);
}
static __device__ __forceinline__ void stf(void* p, long i, int f32flag, float v) {
    if (f32flag) ((float*)p)[i] = v;
    else ((__hip_bfloat16*)p)[i] = __float2bfloat16(v);
}
// async global->LDS, 16B per lane; LDS dest is wave-uniform base + lane*16
static __device__ __forceinline__ void gl2lds16(const f16* g, f16* l) {
    __builtin_amdgcn_global_load_lds(
        (const __attribute__((address_space(1))) unsigned int*)(const void*)g,
        (__attribute__((address_space(3))) unsigned int*)(void*)l, 16, 0, 0);
}
static __device__ __forceinline__ void barrier_raw() {
    asm volatile("" ::: "memory");
    __builtin_amdgcn_s_barrier();
    asm volatile("" ::: "memory");
}

// ---------------- workspace layout (bytes) ----------------
#define OFF_LOGITS 0L                               // S/logits: 32000 x 1024 f16
#define SZ_LOGITS  (32000L * 1024 * 2)
#define OFF_FEAT   (OFF_LOGITS + SZ_LOGITS)         // feat: 32000 x 768 f16
#define SZ_FEAT    (32000L * 768 * 2)
#define OFF_ATTF   (OFF_FEAT + SZ_FEAT)             // att_feat: 32000 x 768 f16
#define SZ_ATTF    (32000L * 768 * 2)
#define OFF_AWT    (OFF_ATTF + SZ_ATTF)             // attn_w^T: 1024 x 768 f16 (rows>=999 zero)
#define SZ_AWT     (1024L * 768 * 2)
#define OFF_WCT    (OFF_AWT + SZ_AWT)               // Wc^T: 128 x 1536 f16 (rows>=75 zero)
#define SZ_WCT     (128L * 1536 * 2)
#define OFF_BIAS   (OFF_WCT + SZ_WCT)               // f32[128]
#define OFF_AB     (OFF_BIAS + 512)                 // attn_b as f32[1024]
#define OFF_FLAG   (OFF_AB + 4096)                  // int flags[2]
#define OFF_FEATT  (OFF_FLAG + 64)                  // feat^T per batch: 32 x 768 x 1024 f16
#define SZ_FEATT   (32L * 768 * 1024 * 2)
#define NEED_A     (OFF_FEATT + SZ_FEATT)           // ~216 MB

// ---------------- detection (cheap sampling) ----------------
__global__ void detect_kernel(const unsigned int* __restrict__ fv,
                              const unsigned int* __restrict__ m,
                              int mwords, int* __restrict__ flags)
{
    __shared__ int cnt, bits;
    int t = threadIdx.x;
    if (t == 0) { cnt = 0; bits = 0; }
    __syncthreads();
    int c = 0;
    for (int k = t; k < 2048; k += 256) {
        unsigned int w = fv[k];
        unsigned int h0 = w & 0xffffu, h1 = w >> 16;
        unsigned int e0 = (h0 >> 7) & 0xffu, e1 = (h1 >> 7) & 0xffu;
        c += (h0 == 0u || (e0 >= 100u && e0 <= 135u)) ? 1 : 0;
        c += (h1 == 0u || (e1 >= 100u && e1 <= 135u)) ? 1 : 0;
    }
    atomicAdd(&cnt, c);
    int lb = 0;
    for (int k = t; k < mwords; k += 256) {
        unsigned int w = m[k];
        if (w > 1u) lb |= 1;
        if ((k & 1) && w != 0u) lb |= 2;
        unsigned int lo = w & 0xffffu, hi = w >> 16;
        if (!((lo == 0u || lo == 0x3f80u) && (hi == 0u || hi == 0x3f80u))) lb |= 4;
        if (lo == 0x3f80u) lb |= 8;
    }
    if (lb) atomicOr(&bits, lb);
    __syncthreads();
    if (t == 0) {
        int b = bits, f;
        if (!(b & 1))      f = (b & 2) ? 0 : 3;
        else if (!(b & 4)) f = (b & 8) ? 2 : 4;
        else               f = 1;
        flags[0] = f;
        flags[1] = (cnt < 3900) ? 1 : 0;
    }
}

// ---------------- gather: build feat via LDS-staged fv slab (vectorized) ----------------
// grid (16 n-chunks of 63, 32 batches) = 512 blocks (2/CU)
__global__ __launch_bounds__(256) void build_feat_kernel(
    const void* __restrict__ fv, const int* __restrict__ x_idx,
    const void* __restrict__ maskp, const int* __restrict__ flags,
    int xstride, int mstride, f16* __restrict__ feat)
{
    __shared__ f16 sfv[15360];                      // [(c*12+h)*20 + x]
    __shared__ int sx[756];                         // [n_local*12 + h]
    __shared__ unsigned char sm[756];
    int b = blockIdx.y, n0 = blockIdx.x * 63;
    int rows = min(63, 1000 - n0);
    int t = threadIdx.x;
    int isf = flags[1], fm = flags[0];
    if (isf) {                                      // f32: 3840 float4 = 15360 elems
        const float4* src = (const float4*)fv + (long)b * 3840;
        for (int k = t; k < 3840; k += 256) {
            float4 v = src[k];
            f16x4 h; h[0] = (f16)v.x; h[1] = (f16)v.y; h[2] = (f16)v.z; h[3] = (f16)v.w;
            *(f16x4*)&sfv[k * 4] = h;
        }
    } else {                                        // bf16: 1920 uint4 = 8 halfwords each
        const uint4* src = (const uint4*)fv + (long)b * 1920;
        for (int k = t; k < 1920; k += 256) {
            uint4 v = src[k];
            unsigned int wv[4] = {v.x, v.y, v.z, v.w};
            f16x8 h;
            #pragma unroll
            for (int j = 0; j < 4; j++) {
                h[2 * j]     = (f16)__uint_as_float((wv[j] & 0xffffu) << 16);
                h[2 * j + 1] = (f16)__uint_as_float(wv[j] & 0xffff0000u);
            }
            *(f16x8*)&sfv[k * 8] = h;
        }
    }
    for (int k = t; k < rows * 12; k += 256) {
        int n = k / 12, h = k - n * 12;
        sx[k] = x_idx[(long)(n0 + n) * xstride + h];
        long mb = (long)(n0 + n) * mstride + h;
        int mv;
        if (fm == 0)      mv = ((const int*)maskp)[mb] != 0;
        else if (fm == 1) mv = ((const unsigned char*)maskp)[mb] != 0;
        else if (fm == 2) mv = ((const unsigned short*)maskp)[mb] != 0;
        else if (fm == 3) mv = ((const int*)maskp)[mb * 2] != 0;
        else              mv = ((const unsigned int*)maskp)[mb] != 0;
        sm[k] = (unsigned char)mv;
    }
    __syncthreads();
    for (int q = t; q < rows * 192; q += 256) {
        int n = q / 192, r = q - n * 192;
        int e0 = r * 4;
        f16x4 v;
        #pragma unroll
        for (int j = 0; j < 4; j++) {
            int e = e0 + j;
            int h = e % 12;
            int kk = n * 12 + h;
            v[j] = sm[kk] ? (f16)0.f : sfv[e * 20 + sx[kk]];
        }
        *(f16x4*)(feat + ((long)(b * 1000 + n0 + n)) * 768 + e0) = v;
    }
}

// ---------------- transpose into f16; SRC=1: dual-float input, SRC=0: f16 input ----------------
template<int SRC>
__global__ __launch_bounds__(256) void transpose_kernel(
    const void* __restrict__ inp, f16* __restrict__ out, const int* __restrict__ flags,
    int R, int C, int inR, int inC, int ldin, int ldout, long sIn, long sOut)
{
    __shared__ f16 tile[32][33];
    int isf = SRC ? flags[1] : 0;
    int c0 = blockIdx.x * 32, r0 = blockIdx.y * 32;
    int tx = threadIdx.x & 31, ty = threadIdx.x >> 5;
    #pragma unroll
    for (int i = ty; i < 32; i += 8) {
        int r = r0 + i, c = c0 + tx;
        float v = 0.f;
        if (r < inR && c < inC) {
            long idx = (long)blockIdx.z * sIn + (long)r * ldin + c;
            v = SRC ? ldf(inp, idx, isf) : (float)((const f16*)inp)[idx];
        }
        tile[i][tx] = (f16)v;
    }
    __syncthreads();
    #pragma unroll
    for (int i = ty; i < 32; i += 8) {
        int oc = c0 + i, orw = r0 + tx;
        if (oc < C && orw < R)
            out[(long)blockIdx.z * sOut + (long)oc * ldout + orw] = tile[tx][i];
    }
}

// ---------------- combined weights + f32 attn bias ----------------
__global__ __launch_bounds__(256) void build_wc_kernel(
    const void* __restrict__ cls_w, const void* __restrict__ cls_b,
    const void* __restrict__ reg_w, const void* __restrict__ reg_b,
    const void* __restrict__ attn_b, const int* __restrict__ flags,
    f16* __restrict__ wcT, float* __restrict__ biasc, float* __restrict__ abf32)
{
    int isf = flags[1];
    int idx = blockIdx.x * 256 + threadIdx.x;       // 128*1536 = 196608
    if (idx < 128 * 1536) {
        int c = idx / 1536, k = idx - c * 1536;
        float v = 0.f;
        if (c < 2)       v = ldf(cls_w, (long)k * 2 + c, isf);
        else if (c < 75) v = ldf(reg_w, (long)k * 73 + (c - 2), isf);
        wcT[idx] = (f16)v;                           // wcT[c][k], ld 1536
    }
    if (idx < 75)
        biasc[idx] = (idx < 2) ? ldf(cls_b, idx, isf) : ldf(reg_b, idx - 2, isf);
    if (idx < 1024)
        abf32[idx] = (idx < 999) ? ldf(attn_b, idx, isf) : 0.f;
}

// ---------------- softmax over 999 + shifted scatter (in place) ----------------
__global__ __launch_bounds__(256) void softmax_kernel(
    f16* __restrict__ buf, const float* __restrict__ abf32)
{
    int i = blockIdx.x, b = blockIdx.y;
    f16* row = buf + ((long)(b * 1000 + i)) * 1024;
    __shared__ float red[8];
    int t = threadIdx.x;
    int k0 = t * 4;
    f16x4 rv = *(const f16x4*)(row + k0);            // all reads before any write
    float4 ab = *(const float4*)(abf32 + k0);
    float abv[4] = {ab.x, ab.y, ab.z, ab.w};
    float v[4];
    float lmax = -3.4e38f;
    #pragma unroll
    for (int j = 0; j < 4; j++) {
        int k = k0 + j;
        float x = (k < 999) ? (float)rv[j] + abv[j] : -3.4e38f;
        v[j] = x;
        lmax = fmaxf(lmax, x);
    }
    #pragma unroll
    for (int o = 32; o > 0; o >>= 1) lmax = fmaxf(lmax, __shfl_down(lmax, o, 64));
    if ((t & 63) == 0) red[t >> 6] = lmax;
    __syncthreads();
    float gmax = fmaxf(fmaxf(red[0], red[1]), fmaxf(red[2], red[3]));
    float lsum = 0.f;
    #pragma unroll
    for (int j = 0; j < 4; j++) {
        int k = k0 + j;
        float e = (k < 999) ? __expf(v[j] - gmax) : 0.f;
        v[j] = e;
        lsum += e;
    }
    #pragma unroll
    for (int o = 32; o > 0; o >>= 1) lsum += __shfl_down(lsum, o, 64);
    if ((t & 63) == 0) red[4 + (t >> 6)] = lsum;
    __syncthreads();
    float inv = 1.f / (red[4] + red[5] + red[6] + red[7]);
    #pragma unroll
    for (int j = 0; j < 4; j++) {
        int k = k0 + j;
        if (k < 999) row[k + (k >= i ? 1 : 0)] = (f16)(v[j] * inv);
    }
    if (t == 0) row[i] = (f16)0.f;                   // zero diagonal
}

// ---------------- MFMA GEMM ----------------
// non-BKM: double-buffered BK=32 pipeline. Next tile's global_load_lds issue BEFORE
//   s_waitcnt vmcnt(AI+BI) + raw s_barrier -> previous tile's loads (a full compute
//   phase old) are waited, NEW loads stay in flight across the barrier (AITER pattern).
//   Second raw barrier (lgkmcnt only) protects the just-read buffer from overwrite.
// SWZ: 0 none; 2 GEMM1 m-group->XCD; 3 GEMM2 batch->XCD (grid 768).
enum { OUT_F16 = 0, OUT_FINAL = 1 };

template<int MODE, bool CAT, bool BKM, int TM, int TN, int SWZ>
__global__ __launch_bounds__(256, 2) void gemm_kernel(
    const f16* __restrict__ A, const f16* __restrict__ A2, int lda,
    const f16* __restrict__ Bt, int ldb,
    void* __restrict__ Cout, int ldc,
    int M, int Nc, int K,
    long sA, long sB, long sC,
    const float* __restrict__ bias, const void* __restrict__ anchors,
    const int* __restrict__ flags)
{
    int t = threadIdx.x;
    int bx, by, bz;
    if constexpr (SWZ == 2) {          // flat grid: ngroups m-groups x 4 n-blocks
        int bid = blockIdx.x;
        int xcd = bid & 7, s = bid >> 3;
        int g = xcd + 8 * (s >> 2);                  // XCD owns groups g == xcd (mod 8)
        if (g >= (M + TM - 1) / TM) return;
        by = g; bx = s & 3; bz = 0;
    } else if constexpr (SWZ == 3) {   // grid 768 flat: 8 XCD x 4 batches x (8m x 3n)
        int bid = blockIdx.x;
        int xcd = bid & 7, s = bid >> 3;             // s in [0,96)
        bz = xcd * 4 + s / 24;
        int wv = s % 24;
        by = wv / 3; bx = wv - by * 3;
    } else { bx = blockIdx.x; by = blockIdx.y; bz = blockIdx.z; }

    int m0 = by * TM, n0 = bx * TN;
    int z = bz;
    A  += (long)z * sA;
    if (CAT) A2 += (long)z * sA;
    Bt += (long)z * sB;
    int w = t >> 6, lane = t & 63;
    constexpr int NJ = (TM == 128 && TN == 256) ? 8 : ((TN == 256) ? 4 : ((TM == 128) ? 4 : 2));
    int wm = (TM == 128) ? (w & 1) * 64 : 0;
    int wn;
    if constexpr (TM == 128 && TN == 256) wn = (w >> 1) * 128;
    else if constexpr (TN == 256)         wn = w * 64;
    else if constexpr (TM == 128)         wn = (w >> 1) * 64;
    else                                  wn = w * 32;

    int lr = lane & 15, lq = lane >> 4;

    const f32x4 zero4 = {0.f, 0.f, 0.f, 0.f};
    f32x4 acc[4][NJ];
    #pragma unroll
    for (int i = 0; i < 4; i++)
        #pragma unroll
        for (int j = 0; j < NJ; j++) acc[i][j] = zero4;

    if constexpr (!BKM) {
        constexpr int AI = TM / 64;                  // A staging ops per tile
        constexpr int BI = TN / 64;                  // B staging ops per tile
        __shared__ __align__(16) f16 As[2][TM * 32];
        __shared__ __align__(16) f16 Bs[2][TN * 32];
        long aoff[AI], boff[BI];
        #pragma unroll
        for (int i = 0; i < AI; i++) {
            int q = t + i * 256;
            int row = q >> 2, slot = q & 3;
            int c = slot ^ ((row >> 1) & 3);
            aoff[i] = (long)(m0 + row) * lda + c * 8;
        }
        #pragma unroll
        for (int i = 0; i < BI; i++) {
            int q = t + i * 256;
            int row = q >> 2, slot = q & 3;
            int c = slot ^ ((row >> 1) & 3);
            boff[i] = (long)(n0 + row) * ldb + c * 8;
        }
        int lb = w * 64 * 8;                         // wave-uniform LDS base
        auto issue = [&](int kt, int pb) {
            const f16* Ak = A; int kk = kt;
            if (CAT && kt >= 768) { Ak = A2; kk = kt - 768; }
            #pragma unroll
            for (int i = 0; i < AI; i++)
                gl2lds16(Ak + aoff[i] + kk, &As[pb][i * 2048 + lb]);
            #pragma unroll
            for (int i = 0; i < BI; i++)
                gl2lds16(Bt + boff[i] + kt, &Bs[pb][i * 2048 + lb]);
        };
        issue(0, 0);
        int p = 0;
        for (int k0 = 0; k0 < K; k0 += 32) {
            if (k0 + 32 < K) {
                issue(k0 + 32, p ^ 1);
                // wait only the PREVIOUS tile's AI+BI loads; new ones stay in flight
                if constexpr (AI + BI == 6)      asm volatile("s_waitcnt vmcnt(6)" ::: "memory");
                else if constexpr (AI + BI == 3) asm volatile("s_waitcnt vmcnt(3)" ::: "memory");
                else if constexpr (AI + BI == 4) asm volatile("s_waitcnt vmcnt(4)" ::: "memory");
                else                             asm volatile("s_waitcnt vmcnt(0)" ::: "memory");
            } else {
                asm volatile("s_waitcnt vmcnt(0)" ::: "memory");
            }
            barrier_raw();
            f16x8 af[4], bfr[NJ];
            #pragma unroll
            for (int i = 0; i < 4; i++) {
                int r = wm + i * 16 + lr;
                af[i] = *(const f16x8*)&As[p][r * 32 + (lq ^ ((r >> 1) & 3)) * 8];
            }
            #pragma unroll
            for (int j = 0; j < NJ; j++) {
                int r = wn + j * 16 + lr;
                bfr[j] = *(const f16x8*)&Bs[p][r * 32 + (lq ^ ((r >> 1) & 3)) * 8];
            }
            #pragma unroll
            for (int i = 0; i < 4; i++)
                #pragma unroll
                for (int j = 0; j < NJ; j++)
                    acc[i][j] = __builtin_amdgcn_mfma_f32_16x16x32_f16(af[i], bfr[j], acc[i][j], 0, 0, 0);
            asm volatile("s_waitcnt lgkmcnt(0)" ::: "memory");
            barrier_raw();                           // reads done -> safe to overwrite
            p ^= 1;
        }
    } else {
        __shared__ __align__(16) f16 As[128 * 40];
        __shared__ __align__(16) f16 Bs[32 * 132];
        const f16x8 zero8 = {(f16)0, (f16)0, (f16)0, (f16)0, (f16)0, (f16)0, (f16)0, (f16)0};
        const f16x4 zero4h = {(f16)0, (f16)0, (f16)0, (f16)0};
        for (int k0 = 0; k0 < K; k0 += 32) {
            __syncthreads();
            #pragma unroll
            for (int i = 0; i < 2; i++) {
                int q = t + i * 256;
                { int row = q >> 2, kc = (q & 3) * 8;
                  f16x8 av = zero8;
                  if ((m0 + row) < M && (k0 + kc) < K)
                      av = *(const f16x8*)(A + (long)(m0 + row) * lda + k0 + kc);
                  *(f16x8*)&As[row * 40 + kc] = av; }
                { int kr = q >> 4, nc = (q & 15) * 8;
                  f16x4 b0 = zero4h, b1 = zero4h;
                  if ((k0 + kr) < K && (n0 + nc) < Nc) {
                      const f16* p2 = Bt + (long)(k0 + kr) * ldb + n0 + nc;
                      b0 = *(const f16x4*)p2;
                      b1 = *(const f16x4*)(p2 + 4);
                  }
                  *(f16x4*)&Bs[kr * 132 + nc]     = b0;
                  *(f16x4*)&Bs[kr * 132 + nc + 4] = b1; }
            }
            __syncthreads();
            f16x8 af[4], bfr[NJ];
            #pragma unroll
            for (int i = 0; i < 4; i++)
                af[i] = *(const f16x8*)&As[(wm + i * 16 + lr) * 40 + lq * 8];
            #pragma unroll
            for (int j = 0; j < NJ; j++)
                #pragma unroll
                for (int jj = 0; jj < 8; jj++)
                    bfr[j][jj] = Bs[(lq * 8 + jj) * 132 + wn + j * 16 + lr];
            #pragma unroll
            for (int i = 0; i < 4; i++)
                #pragma unroll
                for (int j = 0; j < NJ; j++)
                    acc[i][j] = __builtin_amdgcn_mfma_f32_16x16x32_f16(af[i], bfr[j], acc[i][j], 0, 0, 0);
        }
    }

    int isf = (MODE == OUT_FINAL) ? flags[1] : 0;
    #pragma unroll
    for (int i = 0; i < 4; i++) {
        #pragma unroll
        for (int j = 0; j < NJ; j++) {
            #pragma unroll
            for (int r = 0; r < 4; r++) {
                int gm = m0 + wm + i * 16 + lq * 4 + r;   // C/D: row = quad*4+reg
                int gn = n0 + wn + j * 16 + lr;           //      col = lane&15
                if (MODE == OUT_F16) {
                    if (gm < M && gn < Nc)
                        ((f16*)Cout)[(long)z * sC + (long)gm * ldc + gn] = (f16)acc[i][j][r];
                } else {
                    if (gn < Nc) {                         // Nc=75 real cols
                        float v = acc[i][j][r] + bias[gn];
                        int oc = (gn < 2) ? gn : gn + 2;   // skip anchor cols 2,3
                        if (gn >= 2) v += ldf(anchors, (long)(gm % 1000) * 77 + oc, isf);
                        stf(Cout, (long)gm * 77 + oc, isf, v);
                    } else if (gn < 77) {                  // wasted lanes fill anchor cols 2,3
                        int oc = gn - 73;                  // 75->2, 76->3
                        stf(Cout, (long)gm * 77 + oc, isf,
                            ldf(anchors, (long)(gm % 1000) * 77 + oc, isf));
                    }
                }
            }
        }
    }
}

extern "C" void kernel_launch(void* const* d_in, const int* in_sizes, int n_in,
                              void* d_out, int out_size, void* d_ws, size_t ws_size,
                              hipStream_t stream)
{
    const void* fv      = d_in[0];
    const void* attn_w  = d_in[1];
    const void* attn_b  = d_in[2];
    const void* cls_w   = d_in[3];
    const void* cls_b   = d_in[4];
    const void* reg_w   = d_in[5];
    const void* reg_b   = d_in[6];
    const void* anchors = d_in[7];
    const int*  x_idx   = (const int*)d_in[10];
    const void* maskp   = d_in[11];
    int xstride = (in_sizes[10] < 768000) ? 12 : 768;   // un-broadcast fallback
    int mstride = (in_sizes[11] < 768000) ? 12 : 768;
    int mwords  = in_sizes[11] / 4;                      // int8 worst case, stay in bounds
    if (mwords > 4096) mwords = 4096;

    char* ws = (char*)d_ws;
    f16*   logits = (f16*)(ws + OFF_LOGITS);
    f16*   feat   = (f16*)(ws + OFF_FEAT);
    f16*   attf   = (f16*)(ws + OFF_ATTF);
    f16*   awT    = (f16*)(ws + OFF_AWT);
    f16*   wcT    = (f16*)(ws + OFF_WCT);
    float* biasc  = (float*)(ws + OFF_BIAS);
    float* abf32  = (float*)(ws + OFF_AB);
    int*   flags  = (int*)(ws + OFF_FLAG);
    f16*   featT  = (f16*)(ws + OFF_FEATT);
    bool bigws = ws_size >= (size_t)NEED_A;

    detect_kernel<<<dim3(1), dim3(256), 0, stream>>>(
        (const unsigned int*)fv, (const unsigned int*)maskp, mwords, flags);
    build_feat_kernel<<<dim3(16, 32), dim3(256), 0, stream>>>(
        fv, x_idx, maskp, flags, xstride, mstride, feat);
    // attn_w (768 x 999) -> awT (1024 x 768), rows 999..1023 zero
    transpose_kernel<1><<<dim3(32, 24, 1), dim3(256), 0, stream>>>(
        attn_w, awT, flags, 768, 1024, 768, 999, 999, 768, 0, 0);
    build_wc_kernel<<<dim3(768), dim3(256), 0, stream>>>(
        cls_w, cls_b, reg_w, reg_b, attn_b, flags, wcT, biasc, abf32);

    // GEMM1: logits = feat @ attn_w  (M=32000, N=1024 padded, K=768), dbuf pipeline
    gemm_kernel<OUT_F16, false, false, 128, 256, 2><<<dim3(1024), dim3(256), 0, stream>>>(
        feat, nullptr, 768, awT, 768, logits, 1024, 32000, 1024, 768, 0, 0, 0,
        nullptr, nullptr, flags);
    softmax_kernel<<<dim3(1000, 32), dim3(256), 0, stream>>>(logits, abf32);
    // GEMM2 (batched): att_feat = S @ feat  (M=1000, N=768, K=1024 padded, 32 batches)
    if (bigws) {
        transpose_kernel<0><<<dim3(24, 32, 32), dim3(256), 0, stream>>>(
            feat, featT, flags, 1024, 768, 1000, 768, 768, 1024, 768000L, 786432L);
        gemm_kernel<OUT_F16, false, false, 128, 256, 3><<<dim3(768), dim3(256), 0, stream>>>(
            logits, nullptr, 1024, featT, 1024, attf, 768, 1000, 768, 1024,
            1024000L, 786432L, 768000L, nullptr, nullptr, flags);
    } else {
        gemm_kernel<OUT_F16, false, true, 128, 128, 0><<<dim3(6, 8, 32), dim3(256), 0, stream>>>(
            logits, nullptr, 1024, feat, 768, attf, 768, 1000, 768, 1000,
            1024000L, 768000L, 768000L, nullptr, nullptr, flags);
    }
    // GEMM3: out = [att_feat | feat] @ Wc, fused epilogue; TM=64/TN=128 -> 500 blocks
    gemm_kernel<OUT_FINAL, true, false, 64, 128, 0><<<dim3(1, 500, 1), dim3(256), 0, stream>>>(
        attf, feat, 768, wcT, 1536, d_out, 77, 32000, 75, 1536, 0, 0, 0,
        biasc, anchors, flags);
}

// Round 10
// 347.623 us; speedup vs baseline: 1.3485x; 1.0787x over previous
//
#include <hip/hip_runtime.h>
#include <hip/hip_bf16.h>

typedef _Float16 f16;
typedef _Float16 f16x4 __attribute__((ext_vector_type(4)));
typedef _Float16 f16x8 __attribute__((ext_vector_type(8)));
typedef float    f32x4 __attribute__((ext_vector_type(4)));

static __device__ __forceinline__ float bf2f(__hip_bfloat16 x) { return __bfloat162float(x); }
// dual-dtype float load/store: f32flag=1 -> float*, else bf16*
static __device__ __forceinline__ float ldf(const void* p, long i, int f32flag) {
    return f32flag ? ((const float*)p)[i] : bf2f(((const __hip_bfloat16*)p)[i]);
}
static __device__ __forceinline__ void stf(void* p, long i, int f32flag, float v) {
    if (f32flag) ((float*)p)[i] = v;
    else ((__hip_bfloat16*)p)[i] = __float2bfloat16(v);
}
// async global->LDS, 16B per lane; LDS dest is wave-uniform base + lane*16
static __device__ __forceinline__ void gl2lds16(const f16* g, f16* l) {
    __builtin_amdgcn_global_load_lds(
        (const __attribute__((address_space(1))) unsigned int*)(const void*)g,
        (__attribute__((address_space(3))) unsigned int*)(void*)l, 16, 0, 0);
}

// ---------------- workspace layout (bytes) ----------------
#define OFF_LOGITS 0L                               // S/logits: 32000 x 1024 f16
#define SZ_LOGITS  (32000L * 1024 * 2)
#define OFF_FEAT   (OFF_LOGITS + SZ_LOGITS)         // feat: 32000 x 768 f16
#define SZ_FEAT    (32000L * 768 * 2)
#define OFF_ATTF   (OFF_FEAT + SZ_FEAT)             // att_feat: 32000 x 768 f16
#define SZ_ATTF    (32000L * 768 * 2)
#define OFF_AWT    (OFF_ATTF + SZ_ATTF)             // attn_w^T: 1024 x 768 f16 (rows>=999 zero)
#define SZ_AWT     (1024L * 768 * 2)
#define OFF_WCT    (OFF_AWT + SZ_AWT)               // Wc^T: 128 x 1536 f16 (rows>=75 zero)
#define SZ_WCT     (128L * 1536 * 2)
#define OFF_BIAS   (OFF_WCT + SZ_WCT)               // f32[128]
#define OFF_AB     (OFF_BIAS + 512)                 // attn_b as f32[1024]
#define OFF_FLAG   (OFF_AB + 4096)                  // int flags[2]
#define OFF_FEATT  (OFF_FLAG + 64)                  // feat^T per batch: 32 x 768 x 1024 f16
#define SZ_FEATT   (32L * 768 * 1024 * 2)
#define NEED_A     (OFF_FEATT + SZ_FEATT)           // ~216 MB

// ---------------- detection (cheap sampling) ----------------
__global__ void detect_kernel(const unsigned int* __restrict__ fv,
                              const unsigned int* __restrict__ m,
                              int mwords, int* __restrict__ flags)
{
    __shared__ int cnt, bits;
    int t = threadIdx.x;
    if (t == 0) { cnt = 0; bits = 0; }
    __syncthreads();
    int c = 0;
    for (int k = t; k < 2048; k += 256) {
        unsigned int w = fv[k];
        unsigned int h0 = w & 0xffffu, h1 = w >> 16;
        unsigned int e0 = (h0 >> 7) & 0xffu, e1 = (h1 >> 7) & 0xffu;
        c += (h0 == 0u || (e0 >= 100u && e0 <= 135u)) ? 1 : 0;
        c += (h1 == 0u || (e1 >= 100u && e1 <= 135u)) ? 1 : 0;
    }
    atomicAdd(&cnt, c);
    int lb = 0;
    for (int k = t; k < mwords; k += 256) {
        unsigned int w = m[k];
        if (w > 1u) lb |= 1;
        if ((k & 1) && w != 0u) lb |= 2;
        unsigned int lo = w & 0xffffu, hi = w >> 16;
        if (!((lo == 0u || lo == 0x3f80u) && (hi == 0u || hi == 0x3f80u))) lb |= 4;
        if (lo == 0x3f80u) lb |= 8;
    }
    if (lb) atomicOr(&bits, lb);
    __syncthreads();
    if (t == 0) {
        int b = bits, f;
        if (!(b & 1))      f = (b & 2) ? 0 : 3;
        else if (!(b & 4)) f = (b & 8) ? 2 : 4;
        else               f = 1;
        flags[0] = f;
        flags[1] = (cnt < 3900) ? 1 : 0;
    }
}

// ---------------- gather: build feat via LDS-staged fv slab (vectorized) ----------------
__global__ __launch_bounds__(256) void build_feat_kernel(
    const void* __restrict__ fv, const int* __restrict__ x_idx,
    const void* __restrict__ maskp, const int* __restrict__ flags,
    int xstride, int mstride, f16* __restrict__ feat)
{
    __shared__ f16 sfv[15360];                      // [(c*12+h)*20 + x]
    __shared__ int sx[756];                         // [n_local*12 + h]
    __shared__ unsigned char sm[756];
    int b = blockIdx.y, n0 = blockIdx.x * 63;
    int rows = min(63, 1000 - n0);
    int t = threadIdx.x;
    int isf = flags[1], fm = flags[0];
    if (isf) {                                      // f32: 3840 float4
        const float4* src = (const float4*)fv + (long)b * 3840;
        for (int k = t; k < 3840; k += 256) {
            float4 v = src[k];
            f16x4 h; h[0] = (f16)v.x; h[1] = (f16)v.y; h[2] = (f16)v.z; h[3] = (f16)v.w;
            *(f16x4*)&sfv[k * 4] = h;
        }
    } else {                                        // bf16: 1920 uint4
        const uint4* src = (const uint4*)fv + (long)b * 1920;
        for (int k = t; k < 1920; k += 256) {
            uint4 v = src[k];
            unsigned int wv[4] = {v.x, v.y, v.z, v.w};
            f16x8 h;
            #pragma unroll
            for (int j = 0; j < 4; j++) {
                h[2 * j]     = (f16)__uint_as_float((wv[j] & 0xffffu) << 16);
                h[2 * j + 1] = (f16)__uint_as_float(wv[j] & 0xffff0000u);
            }
            *(f16x8*)&sfv[k * 8] = h;
        }
    }
    for (int k = t; k < rows * 12; k += 256) {
        int n = k / 12, h = k - n * 12;
        sx[k] = x_idx[(long)(n0 + n) * xstride + h];
        long mb = (long)(n0 + n) * mstride + h;
        int mv;
        if (fm == 0)      mv = ((const int*)maskp)[mb] != 0;
        else if (fm == 1) mv = ((const unsigned char*)maskp)[mb] != 0;
        else if (fm == 2) mv = ((const unsigned short*)maskp)[mb] != 0;
        else if (fm == 3) mv = ((const int*)maskp)[mb * 2] != 0;
        else              mv = ((const unsigned int*)maskp)[mb] != 0;
        sm[k] = (unsigned char)mv;
    }
    __syncthreads();
    for (int q = t; q < rows * 192; q += 256) {
        int n = q / 192, r = q - n * 192;
        int e0 = r * 4;
        f16x4 v;
        #pragma unroll
        for (int j = 0; j < 4; j++) {
            int e = e0 + j;
            int h = e % 12;
            int kk = n * 12 + h;
            v[j] = sm[kk] ? (f16)0.f : sfv[e * 20 + sx[kk]];
        }
        *(f16x4*)(feat + ((long)(b * 1000 + n0 + n)) * 768 + e0) = v;
    }
}

// ---------------- prep: transpose attn_w -> awT  +  wc/bias/abf32 (one dispatch) ----------------
// grid 1536: blocks [0,768) transpose tiles; [768,1536) weight packing
__global__ __launch_bounds__(256) void prep_kernel(
    const void* __restrict__ attn_w,
    const void* __restrict__ cls_w, const void* __restrict__ cls_b,
    const void* __restrict__ reg_w, const void* __restrict__ reg_b,
    const void* __restrict__ attn_b, const int* __restrict__ flags,
    f16* __restrict__ awT, f16* __restrict__ wcT,
    float* __restrict__ biasc, float* __restrict__ abf32)
{
    int isf = flags[1];
    int bid = blockIdx.x;
    int t = threadIdx.x;
    if (bid < 768) {
        // attn_w (768 x 999, ld 999) -> awT (1024 x 768, ld 768), rows>=999 zero
        __shared__ f16 tile[32][33];
        int c0 = (bid % 32) * 32, r0 = (bid / 32) * 32;    // c: 0..1023, r: 0..767
        int tx = t & 31, ty = t >> 5;
        #pragma unroll
        for (int i = ty; i < 32; i += 8) {
            int r = r0 + i, c = c0 + tx;
            float v = 0.f;
            if (r < 768 && c < 999) v = ldf(attn_w, (long)r * 999 + c, isf);
            tile[i][tx] = (f16)v;
        }
        __syncthreads();
        #pragma unroll
        for (int i = ty; i < 32; i += 8) {
            int oc = c0 + i, orw = r0 + tx;
            awT[(long)oc * 768 + orw] = tile[tx][i];
        }
    } else {
        int idx = (bid - 768) * 256 + t;            // 128*1536 = 196608
        if (idx < 128 * 1536) {
            int c = idx / 1536, k = idx - c * 1536;
            float v = 0.f;
            if (c < 2)       v = ldf(cls_w, (long)k * 2 + c, isf);
            else if (c < 75) v = ldf(reg_w, (long)k * 73 + (c - 2), isf);
            wcT[idx] = (f16)v;                       // wcT[c][k], ld 1536
        }
        if (idx < 75)
            biasc[idx] = (idx < 2) ? ldf(cls_b, idx, isf) : ldf(reg_b, idx - 2, isf);
        if (idx < 1024)
            abf32[idx] = (idx < 999) ? ldf(attn_b, idx, isf) : 0.f;
    }
}

// ---------------- post: feat->featT transpose + softmax-scatter (one dispatch) ----------------
// grid 24576 + 32000: blocks [0,24576) transpose (skipped if featT null); rest softmax rows
__global__ __launch_bounds__(256) void post_kernel(
    f16* __restrict__ buf, const float* __restrict__ abf32,
    const f16* __restrict__ feat, f16* __restrict__ featT)
{
    int bid = blockIdx.x;
    int t = threadIdx.x;
    if (bid < 24576) {
        if (!featT) return;
        // feat (1000 x 768 per batch, ld 768) -> featT (768 x 1024 per batch, ld 1024)
        __shared__ f16 tile[32][33];
        int bx = bid % 24, rq = bid / 24;
        int by = rq % 32, bz = rq / 32;
        int c0 = bx * 32, r0 = by * 32;              // c: 0..767 (cols), r: 0..1023 (rows)
        int tx = t & 31, ty = t >> 5;
        const f16* src = feat + (long)bz * 768000;
        #pragma unroll
        for (int i = ty; i < 32; i += 8) {
            int r = r0 + i, c = c0 + tx;
            f16 v = (f16)0.f;
            if (r < 1000) v = src[(long)r * 768 + c];
            tile[i][tx] = v;
        }
        __syncthreads();
        f16* dst = featT + (long)bz * 786432;
        #pragma unroll
        for (int i = ty; i < 32; i += 8) {
            int oc = c0 + i, orw = r0 + tx;
            dst[(long)oc * 1024 + orw] = tile[tx][i];
        }
    } else {
        int rid = bid - 24576;
        int i = rid % 1000, b = rid / 1000;
        f16* row = buf + ((long)(b * 1000 + i)) * 1024;
        __shared__ float red[8];
        int k0 = t * 4;
        f16x4 rv = *(const f16x4*)(row + k0);        // all reads before any write
        float4 ab = *(const float4*)(abf32 + k0);
        float abv[4] = {ab.x, ab.y, ab.z, ab.w};
        float v[4];
        float lmax = -3.4e38f;
        #pragma unroll
        for (int j = 0; j < 4; j++) {
            int k = k0 + j;
            float x = (k < 999) ? (float)rv[j] + abv[j] : -3.4e38f;
            v[j] = x;
            lmax = fmaxf(lmax, x);
        }
        #pragma unroll
        for (int o = 32; o > 0; o >>= 1) lmax = fmaxf(lmax, __shfl_down(lmax, o, 64));
        if ((t & 63) == 0) red[t >> 6] = lmax;
        __syncthreads();
        float gmax = fmaxf(fmaxf(red[0], red[1]), fmaxf(red[2], red[3]));
        float lsum = 0.f;
        #pragma unroll
        for (int j = 0; j < 4; j++) {
            int k = k0 + j;
            float e = (k < 999) ? __expf(v[j] - gmax) : 0.f;
            v[j] = e;
            lsum += e;
        }
        #pragma unroll
        for (int o = 32; o > 0; o >>= 1) lsum += __shfl_down(lsum, o, 64);
        if ((t & 63) == 0) red[4 + (t >> 6)] = lsum;
        __syncthreads();
        float inv = 1.f / (red[4] + red[5] + red[6] + red[7]);
        #pragma unroll
        for (int j = 0; j < 4; j++) {
            int k = k0 + j;
            if (k < 999) row[k + (k >= i ? 1 : 0)] = (f16)(v[j] * inv);
        }
        if (t == 0) row[i] = (f16)0.f;               // zero diagonal
    }
}

// ---------------- MFMA GEMM ----------------
// non-BKM: single-buffer BK-chunk K-loop (round-8 proven structure, BK generalized).
//   unguarded global_load_lds(16B) into XOR-swizzled LDS; BK/32 MFMA sweeps per barrier.
// SWZ: 0 none; 2 GEMM1 m-group->XCD; 3 GEMM2 batch->XCD (grid 768).
enum { OUT_F16 = 0, OUT_FINAL = 1 };

template<int MODE, bool CAT, bool BKM, int TM, int TN, int BK, int SWZ>
__global__ __launch_bounds__(256, 2) void gemm_kernel(
    const f16* __restrict__ A, const f16* __restrict__ A2, int lda,
    const f16* __restrict__ Bt, int ldb,
    void* __restrict__ Cout, int ldc,
    int M, int Nc, int K,
    long sA, long sB, long sC,
    const float* __restrict__ bias, const void* __restrict__ anchors,
    const int* __restrict__ flags)
{
    int t = threadIdx.x;
    int bx, by, bz;
    if constexpr (SWZ == 2) {          // flat grid: ngroups m-groups x 4 n-blocks
        int bid = blockIdx.x;
        int xcd = bid & 7, s = bid >> 3;
        int g = xcd + 8 * (s >> 2);                  // XCD owns groups g == xcd (mod 8)
        if (g >= (M + TM - 1) / TM) return;
        by = g; bx = s & 3; bz = 0;
    } else if constexpr (SWZ == 3) {   // grid 768 flat: 8 XCD x 4 batches x (8m x 3n)
        int bid = blockIdx.x;
        int xcd = bid & 7, s = bid >> 3;             // s in [0,96)
        bz = xcd * 4 + s / 24;
        int wv = s % 24;
        by = wv / 3; bx = wv - by * 3;
    } else { bx = blockIdx.x; by = blockIdx.y; bz = blockIdx.z; }

    int m0 = by * TM, n0 = bx * TN;
    int z = bz;
    A  += (long)z * sA;
    if (CAT) A2 += (long)z * sA;
    Bt += (long)z * sB;
    int w = t >> 6, lane = t & 63;
    constexpr int NJ = (TM == 128 && TN == 256) ? 8 : ((TN == 256) ? 4 : ((TM == 128) ? 4 : 2));
    int wm = (TM == 128) ? (w & 1) * 64 : 0;
    int wn;
    if constexpr (TM == 128 && TN == 256) wn = (w >> 1) * 128;
    else if constexpr (TN == 256)         wn = w * 64;
    else if constexpr (TM == 128)         wn = (w >> 1) * 64;
    else                                  wn = w * 32;

    int lr = lane & 15, lq = lane >> 4;

    const f32x4 zero4 = {0.f, 0.f, 0.f, 0.f};
    f32x4 acc[4][NJ];
    #pragma unroll
    for (int i = 0; i < 4; i++)
        #pragma unroll
        for (int j = 0; j < NJ; j++) acc[i][j] = zero4;

    if constexpr (!BKM) {
        constexpr int CH  = BK / 8;                  // 16B chunks per row
        constexpr int AI  = TM * BK / 2048;          // staging ops (2048 elems each)
        constexpr int BI  = TN * BK / 2048;
        constexpr int RPO = 2048 / BK;               // rows per staging op (RPO % CH == 0)
        __shared__ __align__(16) f16 As[TM * BK];
        __shared__ __align__(16) f16 Bs[TN * BK];
        int row0 = t / CH, slot = t % CH;
        int csw = slot ^ (row0 & (CH - 1));
        long aoffB = (long)(m0 + row0) * lda + csw * 8;
        long boffB = (long)(n0 + row0) * ldb + csw * 8;
        for (int k0 = 0; k0 < K; k0 += BK) {
            const f16* Ak = A; int kk = k0;
            if (CAT && k0 >= 768) { Ak = A2; kk = k0 - 768; }
            __syncthreads();
            #pragma unroll
            for (int i = 0; i < AI; i++)
                gl2lds16(Ak + aoffB + (long)(i * RPO) * lda + kk, &As[i * 2048 + w * 512]);
            #pragma unroll
            for (int i = 0; i < BI; i++)
                gl2lds16(Bt + boffB + (long)(i * RPO) * ldb + k0, &Bs[i * 2048 + w * 512]);
            __syncthreads();                         // drains vmcnt before barrier
            #pragma unroll
            for (int ks = 0; ks < BK / 32; ks++) {
                f16x8 af[4], bfr[NJ];
                #pragma unroll
                for (int i = 0; i < 4; i++) {
                    int r = wm + i * 16 + lr;
                    int cc = (lq + ks * 4) ^ (r & (CH - 1));
                    af[i] = *(const f16x8*)&As[r * BK + cc * 8];
                }
                #pragma unroll
                for (int j = 0; j < NJ; j++) {
                    int r = wn + j * 16 + lr;
                    int cc = (lq + ks * 4) ^ (r & (CH - 1));
                    bfr[j] = *(const f16x8*)&Bs[r * BK + cc * 8];
                }
                #pragma unroll
                for (int i = 0; i < 4; i++)
                    #pragma unroll
                    for (int j = 0; j < NJ; j++)
                        acc[i][j] = __builtin_amdgcn_mfma_f32_16x16x32_f16(af[i], bfr[j], acc[i][j], 0, 0, 0);
            }
        }
    } else {
        __shared__ __align__(16) f16 As[128 * 40];
        __shared__ __align__(16) f16 Bs[32 * 132];
        const f16x8 zero8 = {(f16)0, (f16)0, (f16)0, (f16)0, (f16)0, (f16)0, (f16)0, (f16)0};
        const f16x4 zero4h = {(f16)0, (f16)0, (f16)0, (f16)0};
        for (int k0 = 0; k0 < K; k0 += 32) {
            __syncthreads();
            #pragma unroll
            for (int i = 0; i < 2; i++) {
                int q = t + i * 256;
                { int row = q >> 2, kc = (q & 3) * 8;
                  f16x8 av = zero8;
                  if ((m0 + row) < M && (k0 + kc) < K)
                      av = *(const f16x8*)(A + (long)(m0 + row) * lda + k0 + kc);
                  *(f16x8*)&As[row * 40 + kc] = av; }
                { int kr = q >> 4, nc = (q & 15) * 8;
                  f16x4 b0 = zero4h, b1 = zero4h;
                  if ((k0 + kr) < K && (n0 + nc) < Nc) {
                      const f16* p2 = Bt + (long)(k0 + kr) * ldb + n0 + nc;
                      b0 = *(const f16x4*)p2;
                      b1 = *(const f16x4*)(p2 + 4);
                  }
                  *(f16x4*)&Bs[kr * 132 + nc]     = b0;
                  *(f16x4*)&Bs[kr * 132 + nc + 4] = b1; }
            }
            __syncthreads();
            f16x8 af[4], bfr[NJ];
            #pragma unroll
            for (int i = 0; i < 4; i++)
                af[i] = *(const f16x8*)&As[(wm + i * 16 + lr) * 40 + lq * 8];
            #pragma unroll
            for (int j = 0; j < NJ; j++)
                #pragma unroll
                for (int jj = 0; jj < 8; jj++)
                    bfr[j][jj] = Bs[(lq * 8 + jj) * 132 + wn + j * 16 + lr];
            #pragma unroll
            for (int i = 0; i < 4; i++)
                #pragma unroll
                for (int j = 0; j < NJ; j++)
                    acc[i][j] = __builtin_amdgcn_mfma_f32_16x16x32_f16(af[i], bfr[j], acc[i][j], 0, 0, 0);
        }
    }

    int isf = (MODE == OUT_FINAL) ? flags[1] : 0;
    #pragma unroll
    for (int i = 0; i < 4; i++) {
        #pragma unroll
        for (int j = 0; j < NJ; j++) {
            #pragma unroll
            for (int r = 0; r < 4; r++) {
                int gm = m0 + wm + i * 16 + lq * 4 + r;   // C/D: row = quad*4+reg
                int gn = n0 + wn + j * 16 + lr;           //      col = lane&15
                if (MODE == OUT_F16) {
                    if (gm < M && gn < Nc)
                        ((f16*)Cout)[(long)z * sC + (long)gm * ldc + gn] = (f16)acc[i][j][r];
                } else {
                    if (gn < Nc) {                         // Nc=75 real cols
                        float v = acc[i][j][r] + bias[gn];
                        int oc = (gn < 2) ? gn : gn + 2;   // skip anchor cols 2,3
                        if (gn >= 2) v += ldf(anchors, (long)(gm % 1000) * 77 + oc, isf);
                        stf(Cout, (long)gm * 77 + oc, isf, v);
                    } else if (gn < 77) {                  // wasted lanes fill anchor cols 2,3
                        int oc = gn - 73;                  // 75->2, 76->3
                        stf(Cout, (long)gm * 77 + oc, isf,
                            ldf(anchors, (long)(gm % 1000) * 77 + oc, isf));
                    }
                }
            }
        }
    }
}

extern "C" void kernel_launch(void* const* d_in, const int* in_sizes, int n_in,
                              void* d_out, int out_size, void* d_ws, size_t ws_size,
                              hipStream_t stream)
{
    const void* fv      = d_in[0];
    const void* attn_w  = d_in[1];
    const void* attn_b  = d_in[2];
    const void* cls_w   = d_in[3];
    const void* cls_b   = d_in[4];
    const void* reg_w   = d_in[5];
    const void* reg_b   = d_in[6];
    const void* anchors = d_in[7];
    const int*  x_idx   = (const int*)d_in[10];
    const void* maskp   = d_in[11];
    int xstride = (in_sizes[10] < 768000) ? 12 : 768;   // un-broadcast fallback
    int mstride = (in_sizes[11] < 768000) ? 12 : 768;
    int mwords  = in_sizes[11] / 4;                      // int8 worst case, stay in bounds
    if (mwords > 4096) mwords = 4096;

    char* ws = (char*)d_ws;
    f16*   logits = (f16*)(ws + OFF_LOGITS);
    f16*   feat   = (f16*)(ws + OFF_FEAT);
    f16*   attf   = (f16*)(ws + OFF_ATTF);
    f16*   awT    = (f16*)(ws + OFF_AWT);
    f16*   wcT    = (f16*)(ws + OFF_WCT);
    float* biasc  = (float*)(ws + OFF_BIAS);
    float* abf32  = (float*)(ws + OFF_AB);
    int*   flags  = (int*)(ws + OFF_FLAG);
    f16*   featT  = (f16*)(ws + OFF_FEATT);
    bool bigws = ws_size >= (size_t)NEED_A;

    detect_kernel<<<dim3(1), dim3(256), 0, stream>>>(
        (const unsigned int*)fv, (const unsigned int*)maskp, mwords, flags);
    build_feat_kernel<<<dim3(16, 32), dim3(256), 0, stream>>>(
        fv, x_idx, maskp, flags, xstride, mstride, feat);
    prep_kernel<<<dim3(1536), dim3(256), 0, stream>>>(
        attn_w, cls_w, cls_b, reg_w, reg_b, attn_b, flags, awT, wcT, biasc, abf32);

    // GEMM1: logits = feat @ attn_w  (M=32000, N=1024 padded, K=768), BK=64
    gemm_kernel<OUT_F16, false, false, 128, 256, 64, 2><<<dim3(1024), dim3(256), 0, stream>>>(
        feat, nullptr, 768, awT, 768, logits, 1024, 32000, 1024, 768, 0, 0, 0,
        nullptr, nullptr, flags);
    // transpose feat->featT + softmax-scatter in one dispatch
    post_kernel<<<dim3(24576 + 32000), dim3(256), 0, stream>>>(
        logits, abf32, feat, bigws ? featT : nullptr);
    // GEMM2 (batched): att_feat = S @ feat  (M=1000, N=768, K=1024 padded, 32 batches), BK=64
    if (bigws) {
        gemm_kernel<OUT_F16, false, false, 128, 256, 64, 3><<<dim3(768), dim3(256), 0, stream>>>(
            logits, nullptr, 1024, featT, 1024, attf, 768, 1000, 768, 1024,
            1024000L, 786432L, 768000L, nullptr, nullptr, flags);
    } else {
        gemm_kernel<OUT_F16, false, true, 128, 128, 32, 0><<<dim3(6, 8, 32), dim3(256), 0, stream>>>(
            logits, nullptr, 1024, feat, 768, attf, 768, 1000, 768, 1000,
            1024000L, 768000L, 768000L, nullptr, nullptr, flags);
    }
    // GEMM3: out = [att_feat | feat] @ Wc, fused epilogue; TM=64/TN=128, BK=128 -> 12 K-iters
    gemm_kernel<OUT_FINAL, true, false, 64, 128, 128, 0><<<dim3(1, 500, 1), dim3(256), 0, stream>>>(
        attf, feat, 768, wcT, 1536, d_out, 77, 32000, 75, 1536, 0, 0, 0,
        biasc, anchors, flags);
}

// Round 11
// 340.883 us; speedup vs baseline: 1.3752x; 1.0198x over previous
//
#include <hip/hip_runtime.h>
#include <hip/hip_bf16.h>

typedef _Float16 f16;
typedef _Float16 f16x4 __attribute__((ext_vector_type(4)));
typedef _Float16 f16x8 __attribute__((ext_vector_type(8)));
typedef float    f32x4 __attribute__((ext_vector_type(4)));

static __device__ __forceinline__ float bf2f(__hip_bfloat16 x) { return __bfloat162float(x); }
// dual-dtype float load/store: f32flag=1 -> float*, else bf16*
static __device__ __forceinline__ float ldf(const void* p, long i, int f32flag) {
    return f32flag ? ((const float*)p)[i] : bf2f(((const __hip_bfloat16*)p)[i]);
}
static __device__ __forceinline__ void stf(void* p, long i, int f32flag, float v) {
    if (f32flag) ((float*)p)[i] = v;
    else ((__hip_bfloat16*)p)[i] = __float2bfloat16(v);
}
// async global->LDS, 16B per lane; LDS dest is wave-uniform base + lane*16
static __device__ __forceinline__ void gl2lds16(const f16* g, f16* l) {
    __builtin_amdgcn_global_load_lds(
        (const __attribute__((address_space(1))) unsigned int*)(const void*)g,
        (__attribute__((address_space(3))) unsigned int*)(void*)l, 16, 0, 0);
}

// ---------------- workspace layout (bytes) ----------------
#define OFF_LOGITS 0L                               // S/logits: 32000 x 1024 f16
#define SZ_LOGITS  (32000L * 1024 * 2)
#define OFF_FEAT   (OFF_LOGITS + SZ_LOGITS)         // feat: 32000 x 768 f16
#define SZ_FEAT    (32000L * 768 * 2)
#define OFF_ATTF   (OFF_FEAT + SZ_FEAT)             // att_feat: 32000 x 768 f16
#define SZ_ATTF    (32000L * 768 * 2)
#define OFF_AWT    (OFF_ATTF + SZ_ATTF)             // attn_w^T: 1024 x 768 f16 (rows>=999 zero)
#define SZ_AWT     (1024L * 768 * 2)
#define OFF_WCT    (OFF_AWT + SZ_AWT)               // Wc^T: 128 x 1536 f16 (rows>=75 zero)
#define SZ_WCT     (128L * 1536 * 2)
#define OFF_BIAS   (OFF_WCT + SZ_WCT)               // f32[128]
#define OFF_AB     (OFF_BIAS + 512)                 // attn_b as f32[1024]
#define OFF_FLAG   (OFF_AB + 4096)                  // int flags[2]
#define OFF_FEATT  (OFF_FLAG + 64)                  // feat^T per batch: 32 x 768 x 1024 f16
#define SZ_FEATT   (32L * 768 * 1024 * 2)
#define NEED_A     (OFF_FEATT + SZ_FEATT)           // ~216 MB

// ---------------- detection (cheap sampling) ----------------
__global__ void detect_kernel(const unsigned int* __restrict__ fv,
                              const unsigned int* __restrict__ m,
                              int mwords, int* __restrict__ flags)
{
    __shared__ int cnt, bits;
    int t = threadIdx.x;
    if (t == 0) { cnt = 0; bits = 0; }
    __syncthreads();
    int c = 0;
    for (int k = t; k < 2048; k += 256) {
        unsigned int w = fv[k];
        unsigned int h0 = w & 0xffffu, h1 = w >> 16;
        unsigned int e0 = (h0 >> 7) & 0xffu, e1 = (h1 >> 7) & 0xffu;
        c += (h0 == 0u || (e0 >= 100u && e0 <= 135u)) ? 1 : 0;
        c += (h1 == 0u || (e1 >= 100u && e1 <= 135u)) ? 1 : 0;
    }
    atomicAdd(&cnt, c);
    int lb = 0;
    for (int k = t; k < mwords; k += 256) {
        unsigned int w = m[k];
        if (w > 1u) lb |= 1;
        if ((k & 1) && w != 0u) lb |= 2;
        unsigned int lo = w & 0xffffu, hi = w >> 16;
        if (!((lo == 0u || lo == 0x3f80u) && (hi == 0u || hi == 0x3f80u))) lb |= 4;
        if (lo == 0x3f80u) lb |= 8;
    }
    if (lb) atomicOr(&bits, lb);
    __syncthreads();
    if (t == 0) {
        int b = bits, f;
        if (!(b & 1))      f = (b & 2) ? 0 : 3;
        else if (!(b & 4)) f = (b & 8) ? 2 : 4;
        else               f = 1;
        flags[0] = f;
        flags[1] = (cnt < 3900) ? 1 : 0;
    }
}

// ---------------- front: build_feat + attn_w transpose + weight packing (one dispatch) ----------------
// grid 2048: [0,512) feat gather; [512,1280) awT transpose; [1280,2048) wc/bias/abf32
__global__ __launch_bounds__(256) void front_kernel(
    const void* __restrict__ fv, const int* __restrict__ x_idx,
    const void* __restrict__ maskp, const int* __restrict__ flags,
    int xstride, int mstride, f16* __restrict__ feat,
    const void* __restrict__ attn_w,
    const void* __restrict__ cls_w, const void* __restrict__ cls_b,
    const void* __restrict__ reg_w, const void* __restrict__ reg_b,
    const void* __restrict__ attn_b,
    f16* __restrict__ awT, f16* __restrict__ wcT,
    float* __restrict__ biasc, float* __restrict__ abf32)
{
    int bid = blockIdx.x;
    int t = threadIdx.x;
    int isf = flags[1], fm = flags[0];
    if (bid < 512) {
        __shared__ f16 sfv[15360];                  // [(c*12+h)*20 + x]
        __shared__ int sx[756];
        __shared__ unsigned char sm[756];
        int b = bid >> 4, n0 = (bid & 15) * 63;
        int rows = min(63, 1000 - n0);
        if (isf) {                                  // f32: 3840 float4
            const float4* src = (const float4*)fv + (long)b * 3840;
            for (int k = t; k < 3840; k += 256) {
                float4 v = src[k];
                f16x4 h; h[0] = (f16)v.x; h[1] = (f16)v.y; h[2] = (f16)v.z; h[3] = (f16)v.w;
                *(f16x4*)&sfv[k * 4] = h;
            }
        } else {                                    // bf16: 1920 uint4
            const uint4* src = (const uint4*)fv + (long)b * 1920;
            for (int k = t; k < 1920; k += 256) {
                uint4 v = src[k];
                unsigned int wv[4] = {v.x, v.y, v.z, v.w};
                f16x8 h;
                #pragma unroll
                for (int j = 0; j < 4; j++) {
                    h[2 * j]     = (f16)__uint_as_float((wv[j] & 0xffffu) << 16);
                    h[2 * j + 1] = (f16)__uint_as_float(wv[j] & 0xffff0000u);
                }
                *(f16x8*)&sfv[k * 8] = h;
            }
        }
        for (int k = t; k < rows * 12; k += 256) {
            int n = k / 12, h = k - n * 12;
            sx[k] = x_idx[(long)(n0 + n) * xstride + h];
            long mb = (long)(n0 + n) * mstride + h;
            int mv;
            if (fm == 0)      mv = ((const int*)maskp)[mb] != 0;
            else if (fm == 1) mv = ((const unsigned char*)maskp)[mb] != 0;
            else if (fm == 2) mv = ((const unsigned short*)maskp)[mb] != 0;
            else if (fm == 3) mv = ((const int*)maskp)[mb * 2] != 0;
            else              mv = ((const unsigned int*)maskp)[mb] != 0;
            sm[k] = (unsigned char)mv;
        }
        __syncthreads();
        for (int q = t; q < rows * 192; q += 256) {
            int n = q / 192, r = q - n * 192;
            int e0 = r * 4;
            f16x4 v;
            #pragma unroll
            for (int j = 0; j < 4; j++) {
                int e = e0 + j;
                int h = e % 12;
                int kk = n * 12 + h;
                v[j] = sm[kk] ? (f16)0.f : sfv[e * 20 + sx[kk]];
            }
            *(f16x4*)(feat + ((long)(b * 1000 + n0 + n)) * 768 + e0) = v;
        }
    } else if (bid < 1280) {
        // attn_w (768 x 999, ld 999) -> awT (1024 x 768, ld 768), rows>=999 zero
        __shared__ f16 tile[32][33];
        int tid = bid - 512;
        int c0 = (tid % 32) * 32, r0 = (tid / 32) * 32;    // c: 0..1023, r: 0..767
        int tx = t & 31, ty = t >> 5;
        #pragma unroll
        for (int i = ty; i < 32; i += 8) {
            int r = r0 + i, c = c0 + tx;
            float v = 0.f;
            if (r < 768 && c < 999) v = ldf(attn_w, (long)r * 999 + c, isf);
            tile[i][tx] = (f16)v;
        }
        __syncthreads();
        #pragma unroll
        for (int i = ty; i < 32; i += 8) {
            int oc = c0 + i, orw = r0 + tx;
            awT[(long)oc * 768 + orw] = tile[tx][i];
        }
    } else {
        int idx = (bid - 1280) * 256 + t;           // 128*1536 = 196608
        if (idx < 128 * 1536) {
            int c = idx / 1536, k = idx - c * 1536;
            float v = 0.f;
            if (c < 2)       v = ldf(cls_w, (long)k * 2 + c, isf);
            else if (c < 75) v = ldf(reg_w, (long)k * 73 + (c - 2), isf);
            wcT[idx] = (f16)v;                       // wcT[c][k], ld 1536
        }
        if (idx < 75)
            biasc[idx] = (idx < 2) ? ldf(cls_b, idx, isf) : ldf(reg_b, idx - 2, isf);
        if (idx < 1024)
            abf32[idx] = (idx < 999) ? ldf(attn_b, idx, isf) : 0.f;
    }
}

// ---------------- post: feat->featT transpose + softmax-scatter (one dispatch) ----------------
__global__ __launch_bounds__(256) void post_kernel(
    f16* __restrict__ buf, const float* __restrict__ abf32,
    const f16* __restrict__ feat, f16* __restrict__ featT)
{
    int bid = blockIdx.x;
    int t = threadIdx.x;
    if (bid < 24576) {
        if (!featT) return;
        __shared__ f16 tile[32][33];
        int bx = bid % 24, rq = bid / 24;
        int by = rq % 32, bz = rq / 32;
        int c0 = bx * 32, r0 = by * 32;
        int tx = t & 31, ty = t >> 5;
        const f16* src = feat + (long)bz * 768000;
        #pragma unroll
        for (int i = ty; i < 32; i += 8) {
            int r = r0 + i, c = c0 + tx;
            f16 v = (f16)0.f;
            if (r < 1000) v = src[(long)r * 768 + c];
            tile[i][tx] = v;
        }
        __syncthreads();
        f16* dst = featT + (long)bz * 786432;
        #pragma unroll
        for (int i = ty; i < 32; i += 8) {
            int oc = c0 + i, orw = r0 + tx;
            dst[(long)oc * 1024 + orw] = tile[tx][i];
        }
    } else {
        int rid = bid - 24576;
        int i = rid % 1000, b = rid / 1000;
        f16* row = buf + ((long)(b * 1000 + i)) * 1024;
        __shared__ float red[8];
        int k0 = t * 4;
        f16x4 rv = *(const f16x4*)(row + k0);        // all reads before any write
        float4 ab = *(const float4*)(abf32 + k0);
        float abv[4] = {ab.x, ab.y, ab.z, ab.w};
        float v[4];
        float lmax = -3.4e38f;
        #pragma unroll
        for (int j = 0; j < 4; j++) {
            int k = k0 + j;
            float x = (k < 999) ? (float)rv[j] + abv[j] : -3.4e38f;
            v[j] = x;
            lmax = fmaxf(lmax, x);
        }
        #pragma unroll
        for (int o = 32; o > 0; o >>= 1) lmax = fmaxf(lmax, __shfl_down(lmax, o, 64));
        if ((t & 63) == 0) red[t >> 6] = lmax;
        __syncthreads();
        float gmax = fmaxf(fmaxf(red[0], red[1]), fmaxf(red[2], red[3]));
        float lsum = 0.f;
        #pragma unroll
        for (int j = 0; j < 4; j++) {
            int k = k0 + j;
            float e = (k < 999) ? __expf(v[j] - gmax) : 0.f;
            v[j] = e;
            lsum += e;
        }
        #pragma unroll
        for (int o = 32; o > 0; o >>= 1) lsum += __shfl_down(lsum, o, 64);
        if ((t & 63) == 0) red[4 + (t >> 6)] = lsum;
        __syncthreads();
        float inv = 1.f / (red[4] + red[5] + red[6] + red[7]);
        #pragma unroll
        for (int j = 0; j < 4; j++) {
            int k = k0 + j;
            if (k < 999) row[k + (k >= i ? 1 : 0)] = (f16)(v[j] * inv);
        }
        if (t == 0) row[i] = (f16)0.f;               // zero diagonal
    }
}

// ---------------- MFMA GEMM ----------------
// !BKM: single-buffer BK-chunk K-loop, global_load_lds(16B), XOR-swizzled LDS.
// BG: B fragments loaded directly from global (small L2-hot B, e.g. wcT) — A-only LDS.
// SWZ: 0 none; 2 GEMM1 m-group->XCD; 3 GEMM2 batch->XCD (grid 768).
enum { OUT_F16 = 0, OUT_FINAL = 1 };

template<int MODE, bool CAT, bool BKM, int TM, int TN, int BK, int SWZ, bool BG>
__global__ __launch_bounds__(256, 2) void gemm_kernel(
    const f16* __restrict__ A, const f16* __restrict__ A2, int lda,
    const f16* __restrict__ Bt, int ldb,
    void* __restrict__ Cout, int ldc,
    int M, int Nc, int K,
    long sA, long sB, long sC,
    const float* __restrict__ bias, const void* __restrict__ anchors,
    const int* __restrict__ flags)
{
    int t = threadIdx.x;
    int bx, by, bz;
    if constexpr (SWZ == 2) {          // flat grid: ngroups m-groups x 4 n-blocks
        int bid = blockIdx.x;
        int xcd = bid & 7, s = bid >> 3;
        int g = xcd + 8 * (s >> 2);                  // XCD owns groups g == xcd (mod 8)
        if (g >= (M + TM - 1) / TM) return;
        by = g; bx = s & 3; bz = 0;
    } else if constexpr (SWZ == 3) {   // grid 768 flat: 8 XCD x 4 batches x (8m x 3n)
        int bid = blockIdx.x;
        int xcd = bid & 7, s = bid >> 3;             // s in [0,96)
        bz = xcd * 4 + s / 24;
        int wv = s % 24;
        by = wv / 3; bx = wv - by * 3;
    } else { bx = blockIdx.x; by = blockIdx.y; bz = blockIdx.z; }

    int m0 = by * TM, n0 = bx * TN;
    int z = bz;
    A  += (long)z * sA;
    if (CAT) A2 += (long)z * sA;
    Bt += (long)z * sB;
    int w = t >> 6, lane = t & 63;
    constexpr int NJ = (TM == 128 && TN == 256) ? 8 : ((TN == 256) ? 4 : ((TM == 128) ? 4 : 2));
    int wm = (TM == 128) ? (w & 1) * 64 : 0;
    int wn;
    if constexpr (TM == 128 && TN == 256) wn = (w >> 1) * 128;
    else if constexpr (TN == 256)         wn = w * 64;
    else if constexpr (TM == 128)         wn = (w >> 1) * 64;
    else                                  wn = w * 32;

    int lr = lane & 15, lq = lane >> 4;

    const f32x4 zero4 = {0.f, 0.f, 0.f, 0.f};
    f32x4 acc[4][NJ];
    #pragma unroll
    for (int i = 0; i < 4; i++)
        #pragma unroll
        for (int j = 0; j < NJ; j++) acc[i][j] = zero4;

    if constexpr (BG) {
        // A staged to LDS; B fragments straight from global (B must be L2-hot & row-padded)
        constexpr int CH  = BK / 8;
        constexpr int AI  = TM * BK / 2048;
        constexpr int RPO = 2048 / BK;
        __shared__ __align__(16) f16 As[TM * BK];
        int row0 = t / CH, slot = t % CH;
        int csw = slot ^ (row0 & (CH - 1));
        long aoffB = (long)(m0 + row0) * lda + csw * 8;
        for (int k0 = 0; k0 < K; k0 += BK) {
            const f16* Ak = A; int kk = k0;
            if (CAT && k0 >= 768) { Ak = A2; kk = k0 - 768; }
            __syncthreads();
            #pragma unroll
            for (int i = 0; i < AI; i++)
                gl2lds16(Ak + aoffB + (long)(i * RPO) * lda + kk, &As[i * 2048 + w * 512]);
            f16x8 ball[BK / 32][NJ];
            #pragma unroll
            for (int ks = 0; ks < BK / 32; ks++)
                #pragma unroll
                for (int j = 0; j < NJ; j++) {
                    int r = wn + j * 16 + lr;
                    ball[ks][j] = *(const f16x8*)(Bt + (long)r * ldb + k0 + (ks * 4 + lq) * 8);
                }
            __syncthreads();
            #pragma unroll
            for (int ks = 0; ks < BK / 32; ks++) {
                f16x8 af[4];
                #pragma unroll
                for (int i = 0; i < 4; i++) {
                    int r = wm + i * 16 + lr;
                    int cc = (lq + ks * 4) ^ (r & (CH - 1));
                    af[i] = *(const f16x8*)&As[r * BK + cc * 8];
                }
                #pragma unroll
                for (int i = 0; i < 4; i++)
                    #pragma unroll
                    for (int j = 0; j < NJ; j++)
                        acc[i][j] = __builtin_amdgcn_mfma_f32_16x16x32_f16(af[i], ball[ks][j], acc[i][j], 0, 0, 0);
            }
        }
    } else if constexpr (!BKM) {
        constexpr int CH  = BK / 8;                  // 16B chunks per row
        constexpr int AI  = TM * BK / 2048;          // staging ops (2048 elems each)
        constexpr int BI  = TN * BK / 2048;
        constexpr int RPO = 2048 / BK;               // rows per staging op
        __shared__ __align__(16) f16 As[TM * BK];
        __shared__ __align__(16) f16 Bs[TN * BK];
        int row0 = t / CH, slot = t % CH;
        int csw = slot ^ (row0 & (CH - 1));
        long aoffB = (long)(m0 + row0) * lda + csw * 8;
        long boffB = (long)(n0 + row0) * ldb + csw * 8;
        for (int k0 = 0; k0 < K; k0 += BK) {
            const f16* Ak = A; int kk = k0;
            if (CAT && k0 >= 768) { Ak = A2; kk = k0 - 768; }
            __syncthreads();
            #pragma unroll
            for (int i = 0; i < AI; i++)
                gl2lds16(Ak + aoffB + (long)(i * RPO) * lda + kk, &As[i * 2048 + w * 512]);
            #pragma unroll
            for (int i = 0; i < BI; i++)
                gl2lds16(Bt + boffB + (long)(i * RPO) * ldb + k0, &Bs[i * 2048 + w * 512]);
            __syncthreads();                         // drains vmcnt before barrier
            #pragma unroll
            for (int ks = 0; ks < BK / 32; ks++) {
                f16x8 af[4], bfr[NJ];
                #pragma unroll
                for (int i = 0; i < 4; i++) {
                    int r = wm + i * 16 + lr;
                    int cc = (lq + ks * 4) ^ (r & (CH - 1));
                    af[i] = *(const f16x8*)&As[r * BK + cc * 8];
                }
                #pragma unroll
                for (int j = 0; j < NJ; j++) {
                    int r = wn + j * 16 + lr;
                    int cc = (lq + ks * 4) ^ (r & (CH - 1));
                    bfr[j] = *(const f16x8*)&Bs[r * BK + cc * 8];
                }
                #pragma unroll
                for (int i = 0; i < 4; i++)
                    #pragma unroll
                    for (int j = 0; j < NJ; j++)
                        acc[i][j] = __builtin_amdgcn_mfma_f32_16x16x32_f16(af[i], bfr[j], acc[i][j], 0, 0, 0);
            }
        }
    } else {
        __shared__ __align__(16) f16 As[128 * 40];
        __shared__ __align__(16) f16 Bs[32 * 132];
        const f16x8 zero8 = {(f16)0, (f16)0, (f16)0, (f16)0, (f16)0, (f16)0, (f16)0, (f16)0};
        const f16x4 zero4h = {(f16)0, (f16)0, (f16)0, (f16)0};
        for (int k0 = 0; k0 < K; k0 += 32) {
            __syncthreads();
            #pragma unroll
            for (int i = 0; i < 2; i++) {
                int q = t + i * 256;
                { int row = q >> 2, kc = (q & 3) * 8;
                  f16x8 av = zero8;
                  if ((m0 + row) < M && (k0 + kc) < K)
                      av = *(const f16x8*)(A + (long)(m0 + row) * lda + k0 + kc);
                  *(f16x8*)&As[row * 40 + kc] = av; }
                { int kr = q >> 4, nc = (q & 15) * 8;
                  f16x4 b0 = zero4h, b1 = zero4h;
                  if ((k0 + kr) < K && (n0 + nc) < Nc) {
                      const f16* p2 = Bt + (long)(k0 + kr) * ldb + n0 + nc;
                      b0 = *(const f16x4*)p2;
                      b1 = *(const f16x4*)(p2 + 4);
                  }
                  *(f16x4*)&Bs[kr * 132 + nc]     = b0;
                  *(f16x4*)&Bs[kr * 132 + nc + 4] = b1; }
            }
            __syncthreads();
            f16x8 af[4], bfr[NJ];
            #pragma unroll
            for (int i = 0; i < 4; i++)
                af[i] = *(const f16x8*)&As[(wm + i * 16 + lr) * 40 + lq * 8];
            #pragma unroll
            for (int j = 0; j < NJ; j++)
                #pragma unroll
                for (int jj = 0; jj < 8; jj++)
                    bfr[j][jj] = Bs[(lq * 8 + jj) * 132 + wn + j * 16 + lr];
            #pragma unroll
            for (int i = 0; i < 4; i++)
                #pragma unroll
                for (int j = 0; j < NJ; j++)
                    acc[i][j] = __builtin_amdgcn_mfma_f32_16x16x32_f16(af[i], bfr[j], acc[i][j], 0, 0, 0);
        }
    }

    int isf = (MODE == OUT_FINAL) ? flags[1] : 0;
    #pragma unroll
    for (int i = 0; i < 4; i++) {
        #pragma unroll
        for (int j = 0; j < NJ; j++) {
            #pragma unroll
            for (int r = 0; r < 4; r++) {
                int gm = m0 + wm + i * 16 + lq * 4 + r;   // C/D: row = quad*4+reg
                int gn = n0 + wn + j * 16 + lr;           //      col = lane&15
                if (MODE == OUT_F16) {
                    if (gm < M && gn < Nc)
                        ((f16*)Cout)[(long)z * sC + (long)gm * ldc + gn] = (f16)acc[i][j][r];
                } else {
                    if (gn < Nc) {                         // Nc=75 real cols
                        float v = acc[i][j][r] + bias[gn];
                        int oc = (gn < 2) ? gn : gn + 2;   // skip anchor cols 2,3
                        if (gn >= 2) v += ldf(anchors, (long)(gm % 1000) * 77 + oc, isf);
                        stf(Cout, (long)gm * 77 + oc, isf, v);
                    } else if (gn < 77) {                  // wasted lanes fill anchor cols 2,3
                        int oc = gn - 73;                  // 75->2, 76->3
                        stf(Cout, (long)gm * 77 + oc, isf,
                            ldf(anchors, (long)(gm % 1000) * 77 + oc, isf));
                    }
                }
            }
        }
    }
}

extern "C" void kernel_launch(void* const* d_in, const int* in_sizes, int n_in,
                              void* d_out, int out_size, void* d_ws, size_t ws_size,
                              hipStream_t stream)
{
    const void* fv      = d_in[0];
    const void* attn_w  = d_in[1];
    const void* attn_b  = d_in[2];
    const void* cls_w   = d_in[3];
    const void* cls_b   = d_in[4];
    const void* reg_w   = d_in[5];
    const void* reg_b   = d_in[6];
    const void* anchors = d_in[7];
    const int*  x_idx   = (const int*)d_in[10];
    const void* maskp   = d_in[11];
    int xstride = (in_sizes[10] < 768000) ? 12 : 768;   // un-broadcast fallback
    int mstride = (in_sizes[11] < 768000) ? 12 : 768;
    int mwords  = in_sizes[11] / 4;                      // int8 worst case, stay in bounds
    if (mwords > 4096) mwords = 4096;

    char* ws = (char*)d_ws;
    f16*   logits = (f16*)(ws + OFF_LOGITS);
    f16*   feat   = (f16*)(ws + OFF_FEAT);
    f16*   attf   = (f16*)(ws + OFF_ATTF);
    f16*   awT    = (f16*)(ws + OFF_AWT);
    f16*   wcT    = (f16*)(ws + OFF_WCT);
    float* biasc  = (float*)(ws + OFF_BIAS);
    float* abf32  = (float*)(ws + OFF_AB);
    int*   flags  = (int*)(ws + OFF_FLAG);
    f16*   featT  = (f16*)(ws + OFF_FEATT);
    bool bigws = ws_size >= (size_t)NEED_A;

    detect_kernel<<<dim3(1), dim3(256), 0, stream>>>(
        (const unsigned int*)fv, (const unsigned int*)maskp, mwords, flags);
    front_kernel<<<dim3(2048), dim3(256), 0, stream>>>(
        fv, x_idx, maskp, flags, xstride, mstride, feat,
        attn_w, cls_w, cls_b, reg_w, reg_b, attn_b, awT, wcT, biasc, abf32);

    // GEMM1: logits = feat @ attn_w  (M=32000, N=1024 padded, K=768), BK=64
    gemm_kernel<OUT_F16, false, false, 128, 256, 64, 2, false><<<dim3(1024), dim3(256), 0, stream>>>(
        feat, nullptr, 768, awT, 768, logits, 1024, 32000, 1024, 768, 0, 0, 0,
        nullptr, nullptr, flags);
    // transpose feat->featT + softmax-scatter in one dispatch
    post_kernel<<<dim3(24576 + 32000), dim3(256), 0, stream>>>(
        logits, abf32, feat, bigws ? featT : nullptr);
    // GEMM2 (batched): att_feat = S @ feat  (M=1000, N=768, K=1024 padded, 32 batches), BK=64
    if (bigws) {
        gemm_kernel<OUT_F16, false, false, 128, 256, 64, 3, false><<<dim3(768), dim3(256), 0, stream>>>(
            logits, nullptr, 1024, featT, 1024, attf, 768, 1000, 768, 1024,
            1024000L, 786432L, 768000L, nullptr, nullptr, flags);
    } else {
        gemm_kernel<OUT_F16, false, true, 128, 128, 32, 0, false><<<dim3(6, 8, 32), dim3(256), 0, stream>>>(
            logits, nullptr, 1024, feat, 768, attf, 768, 1000, 768, 1000,
            1024000L, 768000L, 768000L, nullptr, nullptr, flags);
    }
    // GEMM3: out = [att_feat | feat] @ Wc, fused epilogue; lean BG path (B=wcT from L2),
    // A-only LDS (16 KB), BK=128, TM=64/TN=128 -> 500 blocks, ~3 blocks/CU
    gemm_kernel<OUT_FINAL, true, false, 64, 128, 128, 0, true><<<dim3(1, 500, 1), dim3(256), 0, stream>>>(
        attf, feat, 768, wcT, 1536, d_out, 77, 32000, 75, 1536, 0, 0, 0,
        biasc, anchors, flags);
}